// Round 1
// baseline (2649.778 us; speedup 1.0000x reference)
//
#include <hip/hip_runtime.h>

// Problem constants
#define OBS 64
#define EXT 20
#define HID 84
#define TT  64
#define BB  16

// ws layout (float offsets)
#define OFF_T1INV 0        // 64x64
#define OFF_XT    4096     // 20x64   X^T
#define OFF_NA1   5376     // 20x64   N^T A[:, :64]
#define OFF_ANT1  6656     // 20x64   (AN)[:64,:]^T
#define OFF_ANA1  7936     // 20x64   ((A^T AN)[:64,:])^T
#define OFF_N     9216     // 84x20
#define OFF_AN    10896    // 84x20
#define OFF_D     12576    // 20x20
#define OFF_DLAST 12976    // 20x20
#define OFF_F     13376    // 20x20   F = N^T A N
#define OFF_Q     13776    // [b][i][64]  q_i = T1inv y_i
#define OFF_G     79312    // [i][j][b]   rhs g, overwritten by fwd sweep r~
#define OFF_J     99792    // [i][20][20] Schur inverses
#define OFF_FJ    125392   // [i][20][20] F @ J_i
#define OFF_TS    150992   // [i][j][b]   solution t
#define OFF_PART  171472   // 1008 partial sums
// total 172480 floats = ~690 KB

// ---------------------------------------------------------------------------
// Kernel 1: T1inv = inv(C[:, :64] + L2*I) via Gauss-Jordan w/ partial pivoting
// ---------------------------------------------------------------------------
__global__ __launch_bounds__(256) void k_prep(const float* __restrict__ C,
                                              float* __restrict__ ws) {
    __shared__ float aug[64][129];
    __shared__ float colk[64];
    __shared__ int   piv_s;
    int tid = threadIdx.x;

    for (int id = tid; id < 64 * 64; id += 256) {
        int r = id >> 6, c = id & 63;
        aug[r][c]      = C[r * HID + c] + (r == c ? 1e-3f : 0.0f);
        aug[r][64 + c] = (r == c) ? 1.0f : 0.0f;
    }
    __syncthreads();

    for (int k = 0; k < 64; ++k) {
        // pivot search (wave 0)
        if (tid < 64) {
            float v = (tid >= k) ? fabsf(aug[tid][k]) : -1.0f;
            int idx = tid;
            for (int off = 32; off; off >>= 1) {
                float v2 = __shfl_down(v, off);
                int   i2 = __shfl_down(idx, off);
                if (v2 > v) { v = v2; idx = i2; }
            }
            if (tid == 0) piv_s = idx;
        }
        __syncthreads();
        int p = piv_s;
        if (p != k) {
            for (int c = tid; c < 128; c += 256) {
                float tmp = aug[k][c]; aug[k][c] = aug[p][c]; aug[p][c] = tmp;
            }
        }
        __syncthreads();
        float rp = 1.0f / aug[k][k];
        for (int c = tid; c < 128; c += 256) aug[k][c] *= rp;
        __syncthreads();
        if (tid < 64) colk[tid] = aug[tid][k];
        __syncthreads();
        for (int id = tid; id < 64 * 128; id += 256) {
            int r = id >> 7, c = id & 127;
            if (r != k) aug[r][c] -= colk[r] * aug[k][c];
        }
        __syncthreads();
    }
    for (int id = tid; id < 64 * 64; id += 256) {
        int r = id >> 6, c = id & 63;
        ws[OFF_T1INV + r * 64 + c] = aug[r][64 + c];
    }
}

// ---------------------------------------------------------------------------
// Kernel 2: all small constant matrices
// ---------------------------------------------------------------------------
__global__ __launch_bounds__(256) void k_small(const float* __restrict__ A,
                                               const float* __restrict__ C,
                                               float* __restrict__ ws) {
    __shared__ float Xs[64][20];
    __shared__ float Ns[84][20];
    __shared__ float ANs[84][20];
    int tid = threadIdx.x;

    // X = T1inv @ T2, T2[c][j] = C[c][64+j]
    for (int id = tid; id < 64 * 20; id += 256) {
        int r = id / 20, j = id % 20;
        float s = 0.f;
        for (int c = 0; c < 64; ++c) s += ws[OFF_T1INV + r * 64 + c] * C[c * HID + 64 + j];
        Xs[r][j] = s;
        ws[OFF_XT + j * 64 + r] = s;
    }
    __syncthreads();
    // N = [-X ; I20]
    for (int id = tid; id < HID * 20; id += 256) {
        int p = id / 20, j = id % 20;
        float v = (p < 64) ? -Xs[p][j] : ((p - 64) == j ? 1.f : 0.f);
        Ns[p][j] = v;
        ws[OFF_N + id] = v;
    }
    __syncthreads();
    // AN = A @ N
    for (int id = tid; id < HID * 20; id += 256) {
        int p = id / 20, j = id % 20;
        float s = 0.f;
        for (int m = 0; m < HID; ++m) s += A[p * HID + m] * Ns[m][j];
        ANs[p][j] = s;
        ws[OFF_AN + id] = s;
    }
    __syncthreads();
    // NtN, F = N^T AN, G = (AN)^T AN  -> D, Dlast
    for (int id = tid; id < 400; id += 256) {
        int a = id / 20, b = id % 20;
        float sn = 0.f, sf = 0.f, sg = 0.f;
        for (int p = 0; p < HID; ++p) {
            sn += Ns[p][a] * Ns[p][b];
            sf += Ns[p][a] * ANs[p][b];
            sg += ANs[p][a] * ANs[p][b];
        }
        ws[OFF_F + id]     = sf;
        ws[OFF_D + id]     = sn + sg;
        ws[OFF_DLAST + id] = sn;
    }
    // NA1[j][c] = sum_p N[p][j] A[p][c]; ANA1[j][c] = sum_p AN[p][j] A[p][c]; ANt1[j][c]=AN[c][j]
    for (int id = tid; id < 20 * 64; id += 256) {
        int j = id / 64, c = id % 64;
        float s1 = 0.f, s2 = 0.f;
        for (int p = 0; p < HID; ++p) {
            float av = A[p * HID + c];
            s1 += Ns[p][j] * av;
            s2 += ANs[p][j] * av;
        }
        ws[OFF_NA1 + id]  = s1;
        ws[OFF_ANA1 + id] = s2;
        ws[OFF_ANT1 + id] = ANs[c][j];
    }
}

// ---------------------------------------------------------------------------
// Kernel 3: q[b][i] = T1inv @ y[b][i]
// ---------------------------------------------------------------------------
__global__ __launch_bounds__(64) void k_q(const float* __restrict__ x,
                                          float* __restrict__ ws) {
    int i = blockIdx.x, b = blockIdx.y, r = threadIdx.x;
    __shared__ float yv[64];
    yv[r] = x[(b * TT + i) * 64 + r];
    __syncthreads();
    float s = 0.f;
    const float* Ti = ws + OFF_T1INV + r * 64;
    for (int c = 0; c < 64; ++c) s += Ti[c] * yv[c];
    ws[OFF_Q + (b * TT + i) * 64 + r] = s;
}

// ---------------------------------------------------------------------------
// Kernel 4: g_i = X^T q_i + NA1 q_{i-1} + (i<63)(ANt1 q_{i+1} - ANA1 q_i)
// ---------------------------------------------------------------------------
__global__ __launch_bounds__(64) void k_g(float* __restrict__ ws) {
    int i = blockIdx.x, b = blockIdx.y, tid = threadIdx.x;
    __shared__ float qi[64], qm[64], qp[64];
    const float* qb = ws + OFF_Q + b * TT * 64;
    qi[tid] = qb[i * 64 + tid];
    qm[tid] = (i > 0)  ? qb[(i - 1) * 64 + tid] : 0.f;
    qp[tid] = (i < 63) ? qb[(i + 1) * 64 + tid] : 0.f;
    __syncthreads();
    if (tid < 20) {
        const float* xt = ws + OFF_XT   + tid * 64;
        const float* na = ws + OFF_NA1  + tid * 64;
        const float* at = ws + OFF_ANT1 + tid * 64;
        const float* aa = ws + OFF_ANA1 + tid * 64;
        float s = 0.f;
        if (i < 63) {
            for (int c = 0; c < 64; ++c)
                s += xt[c] * qi[c] + na[c] * qm[c] + at[c] * qp[c] - aa[c] * qi[c];
        } else {
            for (int c = 0; c < 64; ++c)
                s += xt[c] * qi[c] + na[c] * qm[c];
        }
        ws[OFF_G + (i * 20 + tid) * 16 + b] = s;
    }
}

// ---------------------------------------------------------------------------
// Kernel 5a: block-Thomas factor: S_i = D_i - F J_{i-1} F^T, J_i = S_i^{-1}
// single wave, sequential over i (critical path of the whole kernel chain)
// ---------------------------------------------------------------------------
__global__ __launch_bounds__(64) void k_factor(float* __restrict__ ws) {
    int tid = threadIdx.x;
    __shared__ float Fl[400], Dl[400], Dll[400], Jp[400], M1[400];
    __shared__ float aug[20][40];
    __shared__ float colk[20];

    for (int id = tid; id < 400; id += 64) {
        Fl[id]  = ws[OFF_F + id];
        Dl[id]  = ws[OFF_D + id];
        Dll[id] = ws[OFF_DLAST + id];
    }
    __syncthreads();

    for (int i = 0; i < TT; ++i) {
        if (i == 0) {
            for (int id = tid; id < 400; id += 64) {
                int r = id / 20, c = id % 20;
                aug[r][c]      = Dl[id];
                aug[r][20 + c] = (r == c) ? 1.f : 0.f;
            }
        } else {
            // M1 = F @ Jp
            for (int id = tid; id < 400; id += 64) {
                int r = id / 20, c = id % 20;
                float s = 0.f;
                for (int m = 0; m < 20; ++m) s += Fl[r * 20 + m] * Jp[m * 20 + c];
                M1[id] = s;
            }
            __syncthreads();
            const float* Dcur = (i == 63) ? Dll : Dl;
            for (int id = tid; id < 400; id += 64) {
                int r = id / 20, c = id % 20;
                float s = 0.f;
                for (int m = 0; m < 20; ++m) s += M1[r * 20 + m] * Fl[c * 20 + m];
                aug[r][c]      = Dcur[id] - s;
                aug[r][20 + c] = (r == c) ? 1.f : 0.f;
            }
        }
        __syncthreads();
        // Gauss-Jordan inverse (no pivoting; S_i is SPD)
        for (int k = 0; k < 20; ++k) {
            float rp = 1.0f / aug[k][k];
            if (tid < 40) aug[k][tid] *= rp;
            __syncthreads();
            if (tid < 20) colk[tid] = aug[tid][k];
            __syncthreads();
            for (int id = tid; id < 20 * 40; id += 64) {
                int r = id / 40, c = id % 40;
                if (r != k) aug[r][c] -= colk[r] * aug[k][c];
            }
            __syncthreads();
        }
        for (int id = tid; id < 400; id += 64) {
            int r = id / 20, c = id % 20;
            float v = aug[r][20 + c];
            Jp[id] = v;
            ws[OFF_J + i * 400 + id] = v;
        }
        __syncthreads();
        for (int id = tid; id < 400; id += 64) {
            int r = id / 20, c = id % 20;
            float s = 0.f;
            for (int m = 0; m < 20; ++m) s += Fl[r * 20 + m] * Jp[m * 20 + c];
            ws[OFF_FJ + i * 400 + id] = s;
        }
        __syncthreads();
    }
}

// ---------------------------------------------------------------------------
// Kernel 5b: forward sweep per batch: r~_i = g_i + (F J_{i-1}) r~_{i-1}
// ---------------------------------------------------------------------------
__global__ __launch_bounds__(64) void k_fwd(float* __restrict__ ws) {
    int b = blockIdx.x, tid = threadIdx.x;
    __shared__ float rp[20], FJl[400], gi[20];
    if (tid < 20) rp[tid] = ws[OFF_G + tid * 16 + b];
    for (int i = 1; i < TT; ++i) {
        __syncthreads();
        for (int id = tid; id < 400; id += 64) FJl[id] = ws[OFF_FJ + (i - 1) * 400 + id];
        if (tid < 20) gi[tid] = ws[OFF_G + (i * 20 + tid) * 16 + b];
        __syncthreads();
        float v = 0.f;
        if (tid < 20) {
            v = gi[tid];
            for (int m = 0; m < 20; ++m) v += FJl[tid * 20 + m] * rp[m];
        }
        __syncthreads();
        if (tid < 20) {
            rp[tid] = v;
            ws[OFF_G + (i * 20 + tid) * 16 + b] = v;
        }
    }
}

// ---------------------------------------------------------------------------
// Kernel 5c: backward sweep per batch: t_i = J_i (r~_i + F^T t_{i+1})
// ---------------------------------------------------------------------------
__global__ __launch_bounds__(64) void k_bwd(float* __restrict__ ws) {
    int b = blockIdx.x, tid = threadIdx.x;
    __shared__ float Ft[400], Jl[400], tn[20], ri[20], u[20];
    for (int id = tid; id < 400; id += 64) Ft[id] = ws[OFF_F + id];
    for (int id = tid; id < 400; id += 64) Jl[id] = ws[OFF_J + 63 * 400 + id];
    if (tid < 20) ri[tid] = ws[OFF_G + (63 * 20 + tid) * 16 + b];
    __syncthreads();
    if (tid < 20) {
        float s = 0.f;
        for (int m = 0; m < 20; ++m) s += Jl[tid * 20 + m] * ri[m];
        tn[tid] = s;
        ws[OFF_TS + (63 * 20 + tid) * 16 + b] = s;
    }
    for (int i = 62; i >= 0; --i) {
        __syncthreads();
        for (int id = tid; id < 400; id += 64) Jl[id] = ws[OFF_J + i * 400 + id];
        if (tid < 20) ri[tid] = ws[OFF_G + (i * 20 + tid) * 16 + b];
        __syncthreads();
        if (tid < 20) {
            float uu = ri[tid];
            for (int m = 0; m < 20; ++m) uu += Ft[m * 20 + tid] * tn[m];
            u[tid] = uu;
        }
        __syncthreads();
        float s = 0.f;
        if (tid < 20) {
            for (int m = 0; m < 20; ++m) s += Jl[tid * 20 + m] * u[m];
        }
        __syncthreads();
        if (tid < 20) {
            tn[tid] = s;
            ws[OFF_TS + (i * 20 + tid) * 16 + b] = s;
        }
    }
}

// ---------------------------------------------------------------------------
// Kernel 6: e_i = N t_i - AN t_{i-1} + [q_i;0] - A[:, :64] q_{i-1}; partial ssq
// ---------------------------------------------------------------------------
__global__ __launch_bounds__(128) void k_loss(const float* __restrict__ A,
                                              float* __restrict__ ws) {
    int i = blockIdx.x + 1, b = blockIdx.y, tid = threadIdx.x;
    __shared__ float ti[20], tm[20], qi[64], qm[64];
    __shared__ float red[128];
    if (tid < 20) {
        ti[tid] = ws[OFF_TS + (i * 20 + tid) * 16 + b];
        tm[tid] = ws[OFF_TS + ((i - 1) * 20 + tid) * 16 + b];
    }
    if (tid < 64) {
        qi[tid] = ws[OFF_Q + (b * TT + i) * 64 + tid];
        qm[tid] = ws[OFF_Q + (b * TT + i - 1) * 64 + tid];
    }
    __syncthreads();
    float e = 0.f;
    if (tid < HID) {
        int p = tid;
        float s = (p < 64) ? qi[p] : 0.f;
        const float* Np  = ws + OFF_N  + p * 20;
        const float* ANp = ws + OFF_AN + p * 20;
        for (int j = 0; j < 20; ++j) s += Np[j] * ti[j] - ANp[j] * tm[j];
        const float* Ar = A + p * HID;
        for (int c = 0; c < 64; ++c) s -= Ar[c] * qm[c];
        e = s * s;
    }
    red[tid] = e;
    __syncthreads();
    for (int off = 64; off; off >>= 1) {
        if (tid < off) red[tid] += red[tid + off];
        __syncthreads();
    }
    if (tid == 0) ws[OFF_PART + b * 63 + (i - 1)] = red[0];
}

// ---------------------------------------------------------------------------
// Kernel 7: deterministic final reduction -> mean
// ---------------------------------------------------------------------------
__global__ __launch_bounds__(256) void k_reduce(const float* __restrict__ ws,
                                                float* __restrict__ out) {
    __shared__ float red[256];
    int tid = threadIdx.x;
    float s = 0.f;
    for (int id = tid; id < BB * 63; id += 256) s += ws[OFF_PART + id];
    red[tid] = s;
    __syncthreads();
    for (int off = 128; off; off >>= 1) {
        if (tid < off) red[tid] += red[tid + off];
        __syncthreads();
    }
    if (tid == 0) out[0] = red[0] / (float)(BB * (TT - 1) * HID);
}

extern "C" void kernel_launch(void* const* d_in, const int* in_sizes, int n_in,
                              void* d_out, int out_size, void* d_ws, size_t ws_size,
                              hipStream_t stream) {
    (void)in_sizes; (void)n_in; (void)out_size; (void)ws_size;
    const float* x = (const float*)d_in[0];
    const float* A = (const float*)d_in[1];
    const float* C = (const float*)d_in[2];
    float* ws  = (float*)d_ws;
    float* out = (float*)d_out;

    k_prep  <<<dim3(1),            dim3(256), 0, stream>>>(C, ws);
    k_small <<<dim3(1),            dim3(256), 0, stream>>>(A, C, ws);
    k_q     <<<dim3(TT, BB),       dim3(64),  0, stream>>>(x, ws);
    k_g     <<<dim3(TT, BB),       dim3(64),  0, stream>>>(ws);
    k_factor<<<dim3(1),            dim3(64),  0, stream>>>(ws);
    k_fwd   <<<dim3(BB),           dim3(64),  0, stream>>>(ws);
    k_bwd   <<<dim3(BB),           dim3(64),  0, stream>>>(ws);
    k_loss  <<<dim3(TT - 1, BB),   dim3(128), 0, stream>>>(A, ws);
    k_reduce<<<dim3(1),            dim3(256), 0, stream>>>(ws, out);
}

// Round 2
// 747.025 us; speedup vs baseline: 3.5471x; 3.5471x over previous
//
#include <hip/hip_runtime.h>

// Problem constants
#define OBS 64
#define EXT 20
#define HID 84
#define TT  64
#define BB  16

// ws layout (float offsets)
#define OFF_T1INV 0        // 64x64
#define OFF_XT    4096     // 20x64   X^T
#define OFF_NA1   5376     // 20x64   N^T A[:, :64]
#define OFF_ANT1  6656     // 20x64   (AN)[:64,:]^T
#define OFF_ANA1  7936     // 20x64   ((A^T AN)[:64,:])^T
#define OFF_N     9216     // 84x20
#define OFF_AN    10896    // 84x20
#define OFF_D     12576    // 20x20
#define OFF_DLAST 12976    // 20x20
#define OFF_F     13376    // 20x20   F = N^T A N
#define OFF_Q     13776    // [b][i][64]  q_i = T1inv y_i
#define OFF_G     79312    // [i][j][b]   rhs g, overwritten by fwd sweep r~
#define OFF_J     99792    // [i][20][20] Schur inverses (row-major)
#define OFF_Z     125392   // [i][20][20] Z = J F^T    (row-major)
#define OFF_TS    150992   // [i][j][b]   solution t
#define OFF_PART  171472   // 1008 partial sums

// ---------------------------------------------------------------------------
// Kernel 1: T1inv = inv(C[:, :64] + L2*I) via GJ w/ partial pivoting, then
// all small constant matrices (fused; X reads the inverse straight from LDS)
// ---------------------------------------------------------------------------
__global__ __launch_bounds__(256) void k_prepsmall(const float* __restrict__ A,
                                                   const float* __restrict__ C,
                                                   float* __restrict__ ws) {
    __shared__ float aug[64][129];
    __shared__ float colk[64];
    __shared__ int   piv_s;
    __shared__ float Xs[64][20];
    __shared__ float Ns[84][20];
    __shared__ float ANs[84][20];
    int tid = threadIdx.x;

    for (int id = tid; id < 64 * 64; id += 256) {
        int r = id >> 6, c = id & 63;
        aug[r][c]      = C[r * HID + c] + (r == c ? 1e-3f : 0.0f);
        aug[r][64 + c] = (r == c) ? 1.0f : 0.0f;
    }
    __syncthreads();

    for (int k = 0; k < 64; ++k) {
        if (tid < 64) {
            float v = (tid >= k) ? fabsf(aug[tid][k]) : -1.0f;
            int idx = tid;
            for (int off = 32; off; off >>= 1) {
                float v2 = __shfl_down(v, off);
                int   i2 = __shfl_down(idx, off);
                if (v2 > v) { v = v2; idx = i2; }
            }
            if (tid == 0) piv_s = idx;
        }
        __syncthreads();
        int p = piv_s;
        if (p != k) {
            for (int c = tid; c < 128; c += 256) {
                float tmp = aug[k][c]; aug[k][c] = aug[p][c]; aug[p][c] = tmp;
            }
        }
        __syncthreads();
        float rp = 1.0f / aug[k][k];
        for (int c = tid; c < 128; c += 256) aug[k][c] *= rp;
        __syncthreads();
        if (tid < 64) colk[tid] = aug[tid][k];
        __syncthreads();
        for (int id = tid; id < 64 * 128; id += 256) {
            int r = id >> 7, c = id & 127;
            if (r != k) aug[r][c] -= colk[r] * aug[k][c];
        }
        __syncthreads();
    }
    for (int id = tid; id < 64 * 64; id += 256) {
        int r = id >> 6, c = id & 63;
        ws[OFF_T1INV + r * 64 + c] = aug[r][64 + c];
    }
    __syncthreads();

    // ---- small constant matrices ----
    // X = T1inv @ T2 (T1inv read from aug's right half)
    for (int id = tid; id < 64 * 20; id += 256) {
        int r = id / 20, j = id % 20;
        float s = 0.f;
        for (int c = 0; c < 64; ++c) s += aug[r][64 + c] * C[c * HID + 64 + j];
        Xs[r][j] = s;
        ws[OFF_XT + j * 64 + r] = s;
    }
    __syncthreads();
    // N = [-X ; I20]
    for (int id = tid; id < HID * 20; id += 256) {
        int p = id / 20, j = id % 20;
        float v = (p < 64) ? -Xs[p][j] : ((p - 64) == j ? 1.f : 0.f);
        Ns[p][j] = v;
        ws[OFF_N + id] = v;
    }
    __syncthreads();
    // AN = A @ N
    for (int id = tid; id < HID * 20; id += 256) {
        int p = id / 20, j = id % 20;
        float s = 0.f;
        for (int m = 0; m < HID; ++m) s += A[p * HID + m] * Ns[m][j];
        ANs[p][j] = s;
        ws[OFF_AN + id] = s;
    }
    __syncthreads();
    // D = N^T N + (AN)^T AN, F = N^T AN, Dlast = N^T N
    for (int id = tid; id < 400; id += 256) {
        int a = id / 20, b = id % 20;
        float sn = 0.f, sf = 0.f, sg = 0.f;
        for (int p = 0; p < HID; ++p) {
            sn += Ns[p][a] * Ns[p][b];
            sf += Ns[p][a] * ANs[p][b];
            sg += ANs[p][a] * ANs[p][b];
        }
        ws[OFF_F + id]     = sf;
        ws[OFF_D + id]     = sn + sg;
        ws[OFF_DLAST + id] = sn;
    }
    for (int id = tid; id < 20 * 64; id += 256) {
        int j = id / 64, c = id % 64;
        float s1 = 0.f, s2 = 0.f;
        for (int p = 0; p < HID; ++p) {
            float av = A[p * HID + c];
            s1 += Ns[p][j] * av;
            s2 += ANs[p][j] * av;
        }
        ws[OFF_NA1 + id]  = s1;
        ws[OFF_ANA1 + id] = s2;
        ws[OFF_ANT1 + id] = ANs[c][j];
    }
}

// ---------------------------------------------------------------------------
// Kernel 2: q[b][i] = T1inv @ y[b][i]
// ---------------------------------------------------------------------------
__global__ __launch_bounds__(64) void k_q(const float* __restrict__ x,
                                          float* __restrict__ ws) {
    int i = blockIdx.x, b = blockIdx.y, r = threadIdx.x;
    __shared__ float yv[64];
    yv[r] = x[(b * TT + i) * 64 + r];
    __syncthreads();
    float s = 0.f;
    const float* Ti = ws + OFF_T1INV + r * 64;
    for (int c = 0; c < 64; ++c) s += Ti[c] * yv[c];
    ws[OFF_Q + (b * TT + i) * 64 + r] = s;
}

// ---------------------------------------------------------------------------
// Kernel 3: g_i = X^T q_i + NA1 q_{i-1} + (i<63)(ANt1 q_{i+1} - ANA1 q_i)
// ---------------------------------------------------------------------------
__global__ __launch_bounds__(64) void k_g(float* __restrict__ ws) {
    int i = blockIdx.x, b = blockIdx.y, tid = threadIdx.x;
    __shared__ float qi[64], qm[64], qp[64];
    const float* qb = ws + OFF_Q + b * TT * 64;
    qi[tid] = qb[i * 64 + tid];
    qm[tid] = (i > 0)  ? qb[(i - 1) * 64 + tid] : 0.f;
    qp[tid] = (i < 63) ? qb[(i + 1) * 64 + tid] : 0.f;
    __syncthreads();
    if (tid < 20) {
        const float* xt = ws + OFF_XT   + tid * 64;
        const float* na = ws + OFF_NA1  + tid * 64;
        const float* at = ws + OFF_ANT1 + tid * 64;
        const float* aa = ws + OFF_ANA1 + tid * 64;
        float s = 0.f;
        if (i < 63) {
            for (int c = 0; c < 64; ++c)
                s += xt[c] * qi[c] + na[c] * qm[c] + at[c] * qp[c] - aa[c] * qi[c];
        } else {
            for (int c = 0; c < 64; ++c)
                s += xt[c] * qi[c] + na[c] * qm[c];
        }
        ws[OFF_G + (i * 20 + tid) * 16 + b] = s;
    }
}

// ---------------------------------------------------------------------------
// Kernel 4 (mega): factor (wave 0, register-resident GJ via readlane) fused
// with the per-batch forward sweep (waves 1-5, one step behind), then the
// backward sweep with double-buffered J/Z prefetch.
//
// Factor recursion: E_i = D_i - K_{i-1};  GJ on [E | I | F^T] yields
//   J_i = E^{-1} (lanes 20..39) and Z_i = J_i F^T (lanes 40..59);
//   K_i = F Z_i (readlane matmul).  FJ_i = Z_i^T feeds the fwd sweep.
// Early exit: K_i contracts to a fixed point; once |dK| <= 1e-7+1e-6|K|
// (wave-wide), remaining interior steps reuse J/Z (i=63 always recomputed
// with Dlast).
// ---------------------------------------------------------------------------
__global__ __launch_bounds__(512) void k_mega(float* __restrict__ ws) {
    __shared__ float fj[2][20][20];     // FJ_i double buffer (fwd)
    __shared__ float jz[2][800];        // [J | Z] double buffer (bwd)
    __shared__ float tb[2][20][16];     // t_{i} double buffer (bwd)
    __shared__ float rbuf[2][20][16];   // r~ rolling buffer

    int tid  = threadIdx.x;
    int wave = tid >> 6;
    int lane = tid & 63;

    float w[20], Dc[20], Dlc[20], Kc[20], FT[20];
    #pragma unroll
    for (int r = 0; r < 20; ++r) { w[r] = 0.f; Dc[r] = 0.f; Dlc[r] = 0.f; Kc[r] = 0.f; FT[r] = 0.f; }

    if (wave == 0) {
        if (lane < 20) {
            #pragma unroll
            for (int r = 0; r < 20; ++r) {
                Dc[r]  = ws[OFF_D + r * 20 + lane];
                Dlc[r] = ws[OFF_DLAST + r * 20 + lane];
            }
        } else if (lane >= 40 && lane < 60) {
            #pragma unroll
            for (int r = 0; r < 20; ++r)
                FT[r] = ws[OFF_F + (lane - 40) * 20 + r];   // F^T[:,c] = row c of F
        }
    }

    float greg = 0.f;
    if (wave >= 1 && wave <= 5) {
        int gl = tid - 64, b = gl & 15, j = gl >> 4;
        rbuf[0][j][b] = ws[OFF_G + (0 * 20 + j) * 16 + b];  // r~_0 = g_0
        greg          = ws[OFF_G + (1 * 20 + j) * 16 + b];  // prefetch g_1
    }
    __syncthreads();

    int iconv = TT;
    for (int i = 0; i < TT; ++i) {
        if (wave == 0) {
            bool skip = (iconv < TT) && (i < 63);
            if (!skip) {
                // build augmented [E | I | F^T]; lane c owns column c
                #pragma unroll
                for (int r = 0; r < 20; ++r) {
                    float v = 0.f;
                    if (lane < 20)       v = ((i == 63) ? Dlc[r] : Dc[r]) - Kc[r];
                    else if (lane < 40)  v = (r == (lane - 20)) ? 1.f : 0.f;
                    else if (lane < 60)  v = FT[r];
                    w[r] = v;
                }
                // Gauss-Jordan, fully unrolled (E SPD, no pivoting)
                #pragma unroll
                for (int k = 0; k < 20; ++k) {
                    float rp = 1.0f / __shfl(w[k], k);
                    w[k] *= rp;
                    #pragma unroll
                    for (int r = 0; r < 20; ++r) {
                        if (r != k) {
                            float ck = __shfl(w[r], k);   // aug[r][k], uniform
                            w[r] -= ck * w[k];
                        }
                    }
                }
                // K_new = F * Z ; Z column c sits at lane 40+c
                float zs[20];
                #pragma unroll
                for (int r = 0; r < 20; ++r)
                    zs[r] = __shfl(w[r], (lane + 40) & 63);
                float dmax = 0.f, kmax = 0.f;
                #pragma unroll
                for (int r = 0; r < 20; ++r) {
                    float s = 0.f;
                    #pragma unroll
                    for (int m = 0; m < 20; ++m)
                        s += __shfl(FT[m], 40 + r) * zs[m];   // F[r][m], uniform
                    if (lane < 20) {
                        dmax = fmaxf(dmax, fabsf(s - Kc[r]));
                        kmax = fmaxf(kmax, fabsf(s));
                        Kc[r] = s;
                    }
                }
                if (__all(dmax <= 1e-7f + 1e-6f * kmax) && i < 63 && iconv == TT)
                    iconv = i;
            }
            // stores run every step (skip path re-stores identical values)
            if (lane >= 20 && lane < 40) {
                int c = lane - 20;
                #pragma unroll
                for (int r = 0; r < 20; ++r)
                    ws[OFF_J + i * 400 + r * 20 + c] = w[r];   // J row-major (sym)
            } else if (lane >= 40 && lane < 60) {
                int c = lane - 40;
                #pragma unroll
                for (int r = 0; r < 20; ++r) {
                    ws[OFF_Z + i * 400 + r * 20 + c] = w[r];   // Z row-major
                    fj[i & 1][c][r] = w[r];                    // FJ[j][m] = Z[m][j]
                }
            }
        } else if (wave <= 5 && i >= 1) {
            // fwd sweep, one step behind the factor: r~_i = g_i + FJ_{i-1} r~_{i-1}
            int gl = tid - 64, b = gl & 15, j = gl >> 4;
            float s = greg;
            #pragma unroll
            for (int m = 0; m < 20; ++m)
                s += fj[(i - 1) & 1][j][m] * rbuf[(i - 1) & 1][m][b];
            rbuf[i & 1][j][b] = s;
            ws[OFF_G + (i * 20 + j) * 16 + b] = s;             // r~ for bwd
            if (i + 1 < TT) greg = ws[OFF_G + ((i + 1) * 20 + j) * 16 + b];
        }
        __syncthreads();
    }

    __threadfence_block();
    // preload J_63 | Z_63
    for (int id = tid; id < 800; id += 512)
        jz[1][id] = (id < 400) ? ws[OFF_J + 63 * 400 + id]
                               : ws[OFF_Z + 63 * 400 + id - 400];
    __syncthreads();

    // backward sweep: t_i = J_i r~_i + Z_i t_{i+1}
    for (int i = 63; i >= 0; --i) {
        int buf = i & 1;
        float pf0 = 0.f, pf1 = 0.f, pr = 0.f;
        if (i > 0) {
            pf0 = (tid < 400) ? ws[OFF_J + (i - 1) * 400 + tid]
                : (tid < 800) ? ws[OFF_Z + (i - 1) * 400 + tid - 400] : 0.f;
            if (tid < 288) pf1 = ws[OFF_Z + (i - 1) * 400 + tid + 112];
            if (tid >= 64 && tid < 384) {
                int gl = tid - 64, b = gl & 15, j = gl >> 4;
                pr = ws[OFF_G + ((i - 1) * 20 + j) * 16 + b];
            }
        }
        if (tid >= 64 && tid < 384) {
            int gl = tid - 64, b = gl & 15, j = gl >> 4;
            float s = 0.f;
            #pragma unroll
            for (int m = 0; m < 20; ++m)
                s += jz[buf][j * 20 + m] * rbuf[buf][m][b];
            if (i < 63) {
                #pragma unroll
                for (int m = 0; m < 20; ++m)
                    s += jz[buf][400 + j * 20 + m] * tb[(i + 1) & 1][m][b];
            }
            tb[buf][j][b] = s;
            ws[OFF_TS + (i * 20 + j) * 16 + b] = s;
        }
        __syncthreads();
        if (i > 0) {
            if (tid < 800) jz[buf ^ 1][tid] = pf0;
            if (tid < 288) jz[buf ^ 1][tid + 512] = pf1;
            if (tid >= 64 && tid < 384) {
                int gl = tid - 64, b = gl & 15, j = gl >> 4;
                rbuf[buf ^ 1][j][b] = pr;
            }
        }
        __syncthreads();
    }
}

// ---------------------------------------------------------------------------
// Kernel 5: e_i = N t_i - AN t_{i-1} + [q_i;0] - A[:, :64] q_{i-1}; partial ssq
// ---------------------------------------------------------------------------
__global__ __launch_bounds__(128) void k_loss(const float* __restrict__ A,
                                              float* __restrict__ ws) {
    int i = blockIdx.x + 1, b = blockIdx.y, tid = threadIdx.x;
    __shared__ float ti[20], tm[20], qi[64], qm[64];
    __shared__ float red[128];
    if (tid < 20) {
        ti[tid] = ws[OFF_TS + (i * 20 + tid) * 16 + b];
        tm[tid] = ws[OFF_TS + ((i - 1) * 20 + tid) * 16 + b];
    }
    if (tid < 64) {
        qi[tid] = ws[OFF_Q + (b * TT + i) * 64 + tid];
        qm[tid] = ws[OFF_Q + (b * TT + i - 1) * 64 + tid];
    }
    __syncthreads();
    float e = 0.f;
    if (tid < HID) {
        int p = tid;
        float s = (p < 64) ? qi[p] : 0.f;
        const float* Np  = ws + OFF_N  + p * 20;
        const float* ANp = ws + OFF_AN + p * 20;
        for (int j = 0; j < 20; ++j) s += Np[j] * ti[j] - ANp[j] * tm[j];
        const float* Ar = A + p * HID;
        for (int c = 0; c < 64; ++c) s -= Ar[c] * qm[c];
        e = s * s;
    }
    red[tid] = e;
    __syncthreads();
    for (int off = 64; off; off >>= 1) {
        if (tid < off) red[tid] += red[tid + off];
        __syncthreads();
    }
    if (tid == 0) ws[OFF_PART + b * 63 + (i - 1)] = red[0];
}

// ---------------------------------------------------------------------------
// Kernel 6: deterministic final reduction -> mean
// ---------------------------------------------------------------------------
__global__ __launch_bounds__(256) void k_reduce(const float* __restrict__ ws,
                                                float* __restrict__ out) {
    __shared__ float red[256];
    int tid = threadIdx.x;
    float s = 0.f;
    for (int id = tid; id < BB * 63; id += 256) s += ws[OFF_PART + id];
    red[tid] = s;
    __syncthreads();
    for (int off = 128; off; off >>= 1) {
        if (tid < off) red[tid] += red[tid + off];
        __syncthreads();
    }
    if (tid == 0) out[0] = red[0] / (float)(BB * (TT - 1) * HID);
}

extern "C" void kernel_launch(void* const* d_in, const int* in_sizes, int n_in,
                              void* d_out, int out_size, void* d_ws, size_t ws_size,
                              hipStream_t stream) {
    (void)in_sizes; (void)n_in; (void)out_size; (void)ws_size;
    const float* x = (const float*)d_in[0];
    const float* A = (const float*)d_in[1];
    const float* C = (const float*)d_in[2];
    float* ws  = (float*)d_ws;
    float* out = (float*)d_out;

    k_prepsmall<<<dim3(1),          dim3(256), 0, stream>>>(A, C, ws);
    k_q        <<<dim3(TT, BB),     dim3(64),  0, stream>>>(x, ws);
    k_g        <<<dim3(TT, BB),     dim3(64),  0, stream>>>(ws);
    k_mega     <<<dim3(1),          dim3(512), 0, stream>>>(ws);
    k_loss     <<<dim3(TT - 1, BB), dim3(128), 0, stream>>>(A, ws);
    k_reduce   <<<dim3(1),          dim3(256), 0, stream>>>(ws, out);
}

// Round 4
// 606.503 us; speedup vs baseline: 4.3689x; 1.2317x over previous
//
#include <hip/hip_runtime.h>

#define OBS 64
#define EXT 20
#define HID 84
#define TT  64
#define BB  16

// ws float offsets (total 172480 floats = ~690 KB, same as proven round-1/2)
#define OFF_T1INV 0        // 64x64
#define OFF_XT    4096     // 20x64
#define OFF_NA1   5376     // 20x64
#define OFF_ANT1  6656     // 20x64
#define OFF_ANA1  7936     // 20x64
#define OFF_N     9216     // 84x20
#define OFF_AN    10896    // 84x20
#define OFF_D     12576    // 20x20
#define OFF_DLAST 12976    // 20x20
#define OFF_F     13376    // 20x20
#define OFF_Q     13776    // [b][i][64]
#define OFF_G     79312    // [i][b][20] rhs g, overwritten in-place by r~
#define OFF_JG    99792    // [i][20][20] J_i row-major
#define OFF_ZG    125392   // [i][20][20] Z_i = J_i F^T row-major
#define OFF_TS    150992   // [i][b][20] solution t
#define OFF_PART  171472   // 1008 partial sums

#define RDLANE(v, l) __uint_as_float(__builtin_amdgcn_readlane((int)__float_as_uint(v), (l)))

__device__ __forceinline__ void ld20(const float* p, float a[20]) {
    const float4* q = (const float4*)p;
    float4 v0 = q[0], v1 = q[1], v2 = q[2], v3 = q[3], v4 = q[4];
    a[0]=v0.x; a[1]=v0.y; a[2]=v0.z; a[3]=v0.w;
    a[4]=v1.x; a[5]=v1.y; a[6]=v1.z; a[7]=v1.w;
    a[8]=v2.x; a[9]=v2.y; a[10]=v2.z; a[11]=v2.w;
    a[12]=v3.x; a[13]=v3.y; a[14]=v3.z; a[15]=v3.w;
    a[16]=v4.x; a[17]=v4.y; a[18]=v4.z; a[19]=v4.w;
}

__device__ __forceinline__ float dot_bp(const float a[20], int base, float v) {
    float s = 0.f;
    #pragma unroll
    for (int m = 0; m < 20; ++m)
        s += a[m] * __uint_as_float(
            __builtin_amdgcn_ds_bpermute(base + (m << 2), (int)__float_as_uint(v)));
    return s;
}

// ---------------------------------------------------------------------------
// k_prepsmall (round-2 proven structure @512 threads; rp precomputed in the
// pivot phase to remove the read/write race on aug[k][k])
// ---------------------------------------------------------------------------
__global__ __launch_bounds__(512) void k_prepsmall(const float* __restrict__ A,
                                                   const float* __restrict__ C,
                                                   float* __restrict__ ws) {
    __shared__ float aug[64][129];
    __shared__ float colk[64];
    __shared__ int   piv_s;
    __shared__ float rp_s;
    __shared__ float Xs[64][20];
    __shared__ float Ns[84][20];
    __shared__ float ANs[84][20];
    int tid = threadIdx.x;

    for (int id = tid; id < 64 * 64; id += 512) {
        int r = id >> 6, c = id & 63;
        aug[r][c]      = C[r * HID + c] + (r == c ? 1e-3f : 0.0f);
        aug[r][64 + c] = (r == c) ? 1.0f : 0.0f;
    }
    __syncthreads();

    for (int k = 0; k < 64; ++k) {
        if (tid < 64) {
            float v = (tid >= k) ? fabsf(aug[tid][k]) : -1.0f;
            int idx = tid;
            for (int off = 32; off; off >>= 1) {
                float v2 = __shfl_down(v, off);
                int   i2 = __shfl_down(idx, off);
                if (v2 > v) { v = v2; idx = i2; }
            }
            if (tid == 0) { piv_s = idx; rp_s = 1.0f / aug[idx][k]; }
        }
        __syncthreads();
        int p = piv_s;
        if (p != k) {
            for (int c = tid; c < 128; c += 512) {
                float tmp = aug[k][c]; aug[k][c] = aug[p][c]; aug[p][c] = tmp;
            }
        }
        __syncthreads();
        float rp = rp_s;
        for (int c = tid; c < 128; c += 512) aug[k][c] *= rp;
        __syncthreads();
        if (tid < 64) colk[tid] = aug[tid][k];
        __syncthreads();
        for (int id = tid; id < 64 * 128; id += 512) {
            int r = id >> 7, c = id & 127;
            if (r != k) aug[r][c] -= colk[r] * aug[k][c];
        }
        __syncthreads();
    }
    for (int id = tid; id < 64 * 64; id += 512) {
        int r = id >> 6, c = id & 63;
        ws[OFF_T1INV + r * 64 + c] = aug[r][64 + c];
    }
    __syncthreads();

    // X = T1inv @ T2
    for (int id = tid; id < 64 * 20; id += 512) {
        int r = id / 20, j = id % 20;
        float s = 0.f;
        for (int c = 0; c < 64; ++c) s += aug[r][64 + c] * C[c * HID + 64 + j];
        Xs[r][j] = s;
        ws[OFF_XT + j * 64 + r] = s;
    }
    __syncthreads();
    // N = [-X ; I20]
    for (int id = tid; id < HID * 20; id += 512) {
        int p = id / 20, j = id % 20;
        float v = (p < 64) ? -Xs[p][j] : ((p - 64) == j ? 1.f : 0.f);
        Ns[p][j] = v;
        ws[OFF_N + id] = v;
    }
    __syncthreads();
    // AN = A @ N
    for (int id = tid; id < HID * 20; id += 512) {
        int p = id / 20, j = id % 20;
        float s = 0.f;
        for (int m = 0; m < HID; ++m) s += A[p * HID + m] * Ns[m][j];
        ANs[p][j] = s;
        ws[OFF_AN + id] = s;
    }
    __syncthreads();
    // D = N^T N + (AN)^T AN, F = N^T AN, Dlast = N^T N
    for (int id = tid; id < 400; id += 512) {
        int a = id / 20, b = id % 20;
        float sn = 0.f, sf = 0.f, sg = 0.f;
        for (int p = 0; p < HID; ++p) {
            sn += Ns[p][a] * Ns[p][b];
            sf += Ns[p][a] * ANs[p][b];
            sg += ANs[p][a] * ANs[p][b];
        }
        ws[OFF_F + id]     = sf;
        ws[OFF_D + id]     = sn + sg;
        ws[OFF_DLAST + id] = sn;
    }
    for (int id = tid; id < 20 * 64; id += 512) {
        int j = id / 64, c = id % 64;
        float s1 = 0.f, s2 = 0.f;
        for (int p = 0; p < HID; ++p) {
            float av = A[p * HID + c];
            s1 += Ns[p][j] * av;
            s2 += ANs[p][j] * av;
        }
        ws[OFF_NA1 + id]  = s1;
        ws[OFF_ANA1 + id] = s2;
        ws[OFF_ANT1 + id] = ANs[c][j];
    }
}

// ---------------------------------------------------------------------------
// k_q: q[b][i] = T1inv @ y[b][i]   (round-2 proven, verbatim)
// ---------------------------------------------------------------------------
__global__ __launch_bounds__(64) void k_q(const float* __restrict__ x,
                                          float* __restrict__ ws) {
    int i = blockIdx.x, b = blockIdx.y, r = threadIdx.x;
    __shared__ float yv[64];
    yv[r] = x[(b * TT + i) * 64 + r];
    __syncthreads();
    float s = 0.f;
    const float* Ti = ws + OFF_T1INV + r * 64;
    for (int c = 0; c < 64; ++c) s += Ti[c] * yv[c];
    ws[OFF_Q + (b * TT + i) * 64 + r] = s;
}

// ---------------------------------------------------------------------------
// k_g: g_i = X^T q_i + NA1 q_{i-1} + (i<63)(ANt1 q_{i+1} - ANA1 q_i)
// (round-2 proven; only the output layout changed to [i][b][20])
// ---------------------------------------------------------------------------
__global__ __launch_bounds__(64) void k_g(float* __restrict__ ws) {
    int i = blockIdx.x, b = blockIdx.y, tid = threadIdx.x;
    __shared__ float qi[64], qm[64], qp[64];
    const float* qb = ws + OFF_Q + b * TT * 64;
    qi[tid] = qb[i * 64 + tid];
    qm[tid] = (i > 0)  ? qb[(i - 1) * 64 + tid] : 0.f;
    qp[tid] = (i < 63) ? qb[(i + 1) * 64 + tid] : 0.f;
    __syncthreads();
    if (tid < 20) {
        const float* xt = ws + OFF_XT   + tid * 64;
        const float* na = ws + OFF_NA1  + tid * 64;
        const float* at = ws + OFF_ANT1 + tid * 64;
        const float* aa = ws + OFF_ANA1 + tid * 64;
        float s = 0.f;
        if (i < 63) {
            for (int c = 0; c < 64; ++c)
                s += xt[c] * qi[c] + na[c] * qm[c] + at[c] * qp[c] - aa[c] * qi[c];
        } else {
            for (int c = 0; c < 64; ++c)
                s += xt[c] * qi[c] + na[c] * qm[c];
        }
        ws[OFF_G + (i * 16 + b) * 20 + tid] = s;
    }
}

// ---------------------------------------------------------------------------
// k_sweep: wave 0 = Riccati factor (register GJ on the 40x60 bordered system
// [[E,Ft,I],[F,0,0]] -> J, Z, FJ, -K in one pass; round-2 convergence tol);
// FJ handed to waves 1-8 through the round-2-proven LDS double buffer for the
// lag-1 forward sweep (in-place r~ over G); then a register-resident backward
// sweep with 2-unrolled J/Z prefetch, writing t to TS.
// ---------------------------------------------------------------------------
__global__ __launch_bounds__(576) void k_sweep(float* __restrict__ ws) {
    __shared__ float fjs[2][20][20];
    __shared__ int iconv_s;
    int tid = threadIdx.x, wave = tid >> 6, lane = tid & 63;
    if (tid == 0) iconv_s = 63;

    float* G  = ws + OFF_G;
    float* Jg = ws + OFF_JG;
    float* Zg = ws + OFF_ZG;
    float* TS = ws + OFF_TS;

    float Dcol[20], Dlcol[20], Fcomb[20], Kprev[20], fjreg[20];
    if (wave == 0) {
        __builtin_amdgcn_s_setprio(1);
        #pragma unroll
        for (int r = 0; r < 20; ++r) { Dcol[r]=0.f; Dlcol[r]=0.f; Fcomb[r]=0.f; Kprev[r]=0.f; fjreg[r]=0.f; }
        if (lane < 20) {
            #pragma unroll
            for (int r = 0; r < 20; ++r) {
                Dcol[r]  = ws[OFF_D + r * 20 + lane];
                Dlcol[r] = ws[OFF_DLAST + r * 20 + lane];
                Fcomb[r] = ws[OFF_F + r * 20 + lane];        // F column `lane`
            }
        } else if (lane < 40) {
            #pragma unroll
            for (int r = 0; r < 20; ++r)
                Fcomb[r] = ws[OFF_F + (lane - 20) * 20 + r]; // F row `lane-20` (F^T col)
        }
    }

    int b = ((wave - 1) << 1) + (lane >> 5);
    int j = lane & 31;
    int jj = (j < 20) ? j : 0;
    bool actj = (wave >= 1) && (j < 20);
    int bpb = (lane & 32) << 2;
    float rt = 0.f, gnext = 0.f;
    if (actj) {
        rt    = G[(0 * 16 + b) * 20 + j];   // r~_0 = g_0
        gnext = G[(1 * 16 + b) * 20 + j];
    }
    __syncthreads();

    int iconv_loc = 63;
    for (int i = 0; i < TT; ++i) {
        if (wave == 0) {
            bool skip = (i > iconv_loc) && (i < 63);
            if (!skip) {
                float w[40];
                #pragma unroll
                for (int r = 0; r < 20; ++r) {
                    float v;
                    if (lane < 20)      v = ((i == 63) ? Dlcol[r] : Dcol[r]) - Kprev[r];
                    else if (lane < 40) v = Fcomb[r];                  // F^T block
                    else if (lane < 60) v = (r == lane - 40) ? 1.f : 0.f;
                    else                v = 0.f;
                    w[r] = v;
                    w[20 + r] = (lane < 20) ? Fcomb[r] : 0.f;          // [F 0 0]
                }
                #pragma unroll
                for (int k = 0; k < 20; ++k) {
                    float rp = 1.0f / RDLANE(w[k], k);
                    w[k] *= rp;
                    #pragma unroll
                    for (int r = 0; r < 40; ++r) {
                        if (r == k) continue;
                        float ck = RDLANE(w[r], k);
                        w[r] -= ck * w[k];
                    }
                }
                #pragma unroll
                for (int r = 0; r < 20; ++r) fjreg[r] = -w[20 + r];   // FJ[r][c] @ lane 40+c
                // gather K_new (rows 20..39, lanes 20..39) and convergence check
                float dmax = 0.f, kmax = 0.f;
                int gsel = (20 + lane) << 2;
                #pragma unroll
                for (int r = 0; r < 20; ++r) {
                    float kn = -__uint_as_float(__builtin_amdgcn_ds_bpermute(
                        gsel, (int)__float_as_uint(w[20 + r])));
                    dmax = fmaxf(dmax, fabsf(kn - Kprev[r]));
                    kmax = fmaxf(kmax, fabsf(kn));
                    Kprev[r] = kn;
                }
                if (i < 63 && iconv_loc == 63) {
                    if (__all((lane >= 20) || (dmax <= 1e-7f + 1e-6f * kmax))) {
                        iconv_loc = i;
                        if (lane == 0) iconv_s = i;
                    }
                }
                if (lane >= 40 && lane < 60) {
                    int c = lane - 40;
                    #pragma unroll
                    for (int r = 0; r < 20; ++r) {
                        Jg[i * 400 + r * 20 + c] = w[r];       // J row-major (sym)
                        Zg[i * 400 + c * 20 + r] = fjreg[r];   // Z = (FJ)^T row-major
                    }
                }
            }
            // ALWAYS publish FJ_i into the LDS double buffer (skip path republishes)
            if (lane >= 40 && lane < 60) {
                int c = lane - 40;
                #pragma unroll
                for (int r = 0; r < 20; ++r) fjs[i & 1][r][c] = fjreg[r];
            }
        } else if (i >= 1) {
            // fwd step i: r~_i = g_i + FJ_{i-1} r~_{i-1}
            float fr[20];
            #pragma unroll
            for (int m = 0; m < 20; ++m) fr[m] = fjs[(i - 1) & 1][jj][m];
            rt = gnext + dot_bp(fr, bpb, rt);
            if (actj) {
                G[(i * 16 + b) * 20 + j] = rt;
                gnext = (i + 1 < TT) ? G[((i + 1) * 16 + b) * 20 + j] : 0.f;
            }
        }
        __syncthreads();
    }
    __threadfence_block();
    __syncthreads();

    // backward sweep: t_i = J_i r~_i + Z_i t_{i+1}, register-resident, prefetched
    if (wave >= 1) {
        int icv = iconv_s;
        float tn;
        float jr[20], zr[20], jrn[20], zrn[20];
        {
            float j63[20];
            ld20(Jg + 63 * 400 + jj * 20, j63);
            int ix = (62 < icv) ? 62 : icv;
            ld20(Jg + ix * 400 + jj * 20, jr);
            ld20(Zg + ix * 400 + jj * 20, zr);
            tn = dot_bp(j63, bpb, rt);                 // rt == r~_63
            if (actj) TS[(63 * 16 + b) * 20 + j] = tn;
        }
        for (int i = 62; i >= 0; i -= 2) {
            {
                if (i > 0) {
                    int ix = ((i - 1) < icv) ? (i - 1) : icv;
                    ld20(Jg + ix * 400 + jj * 20, jrn);
                    ld20(Zg + ix * 400 + jj * 20, zrn);
                }
                float rtp = actj ? G[(i * 16 + b) * 20 + j] : 0.f;
                float t = dot_bp(jr, bpb, rtp) + dot_bp(zr, bpb, tn);
                if (actj) TS[(i * 16 + b) * 20 + j] = t;
                tn = t;
            }
            if (i > 0) {
                if (i - 1 > 0) {
                    int ix = ((i - 2) < icv) ? (i - 2) : icv;
                    ld20(Jg + ix * 400 + jj * 20, jr);
                    ld20(Zg + ix * 400 + jj * 20, zr);
                }
                float rtp = actj ? G[((i - 1) * 16 + b) * 20 + j] : 0.f;
                float t = dot_bp(jrn, bpb, rtp) + dot_bp(zrn, bpb, tn);
                if (actj) TS[((i - 1) * 16 + b) * 20 + j] = t;
                tn = t;
            }
        }
    }
}

// ---------------------------------------------------------------------------
// k_loss: e_i = N t_i - AN t_{i-1} + [q_i;0] - A[:, :64] q_{i-1}; partial ssq
// (round-2 proven; only the TS read layout changed to [i][b][20])
// ---------------------------------------------------------------------------
__global__ __launch_bounds__(128) void k_loss(const float* __restrict__ A,
                                              float* __restrict__ ws) {
    int i = blockIdx.x + 1, b = blockIdx.y, tid = threadIdx.x;
    __shared__ float ti[20], tm[20], qi[64], qm[64];
    __shared__ float red[128];
    if (tid < 20) {
        ti[tid] = ws[OFF_TS + (i * 16 + b) * 20 + tid];
        tm[tid] = ws[OFF_TS + ((i - 1) * 16 + b) * 20 + tid];
    }
    if (tid < 64) {
        qi[tid] = ws[OFF_Q + (b * TT + i) * 64 + tid];
        qm[tid] = ws[OFF_Q + (b * TT + i - 1) * 64 + tid];
    }
    __syncthreads();
    float e = 0.f;
    if (tid < HID) {
        int p = tid;
        float s = (p < 64) ? qi[p] : 0.f;
        const float* Np  = ws + OFF_N  + p * 20;
        const float* ANp = ws + OFF_AN + p * 20;
        for (int j = 0; j < 20; ++j) s += Np[j] * ti[j] - ANp[j] * tm[j];
        const float* Ar = A + p * HID;
        for (int c = 0; c < 64; ++c) s -= Ar[c] * qm[c];
        e = s * s;
    }
    red[tid] = e;
    __syncthreads();
    for (int off = 64; off; off >>= 1) {
        if (tid < off) red[tid] += red[tid + off];
        __syncthreads();
    }
    if (tid == 0) ws[OFF_PART + b * 63 + (i - 1)] = red[0];
}

// ---------------------------------------------------------------------------
// k_reduce: deterministic final reduction -> mean   (round-2 proven, verbatim)
// ---------------------------------------------------------------------------
__global__ __launch_bounds__(256) void k_reduce(const float* __restrict__ ws,
                                                float* __restrict__ out) {
    __shared__ float red[256];
    int tid = threadIdx.x;
    float s = 0.f;
    for (int id = tid; id < BB * 63; id += 256) s += ws[OFF_PART + id];
    red[tid] = s;
    __syncthreads();
    for (int off = 128; off; off >>= 1) {
        if (tid < off) red[tid] += red[tid + off];
        __syncthreads();
    }
    if (tid == 0) out[0] = red[0] / (float)(BB * (TT - 1) * HID);
}

extern "C" void kernel_launch(void* const* d_in, const int* in_sizes, int n_in,
                              void* d_out, int out_size, void* d_ws, size_t ws_size,
                              hipStream_t stream) {
    (void)in_sizes; (void)n_in; (void)out_size; (void)ws_size;
    const float* x = (const float*)d_in[0];
    const float* A = (const float*)d_in[1];
    const float* C = (const float*)d_in[2];
    float* ws  = (float*)d_ws;
    float* out = (float*)d_out;

    k_prepsmall<<<dim3(1),          dim3(512), 0, stream>>>(A, C, ws);
    k_q        <<<dim3(TT, BB),     dim3(64),  0, stream>>>(x, ws);
    k_g        <<<dim3(TT, BB),     dim3(64),  0, stream>>>(ws);
    k_sweep    <<<dim3(1),          dim3(576), 0, stream>>>(ws);
    k_loss     <<<dim3(TT - 1, BB), dim3(128), 0, stream>>>(A, ws);
    k_reduce   <<<dim3(1),          dim3(256), 0, stream>>>(ws, out);
}

// Round 5
// 318.076 us; speedup vs baseline: 8.3307x; 1.9068x over previous
//
#include <hip/hip_runtime.h>

#define OBS 64
#define EXT 20
#define HID 84
#define TT  64
#define BB  16

// ws float offsets (total 172480 floats = ~690 KB)
#define OFF_T1INV 0        // 64x64
#define OFF_XT    4096     // 20x64
#define OFF_NA1   5376     // 20x64
#define OFF_ANT1  6656     // 20x64
#define OFF_ANA1  7936     // 20x64
#define OFF_N     9216     // 84x20
#define OFF_AN    10896    // 84x20
#define OFF_D     12576    // 20x20
#define OFF_DLAST 12976    // 20x20
#define OFF_F     13376    // 20x20
#define OFF_Q     13776    // [b][i][64]
#define OFF_G     79312    // [i][b][20] rhs g, overwritten in-place by r~
#define OFF_JG    99792    // [i][20][20] J_i row-major
#define OFF_ZG    125392   // [i][20][20] Z_i = J_i F^T row-major
#define OFF_TS    150992   // [i][b][20] solution t
#define OFF_PART  171472   // 1008 partial sums

#define RDLANE(v, l) __uint_as_float(__builtin_amdgcn_readlane((int)__float_as_uint(v), (l)))

__device__ __forceinline__ void ld20(const float* p, float a[20]) {
    const float4* q = (const float4*)p;
    float4 v0 = q[0], v1 = q[1], v2 = q[2], v3 = q[3], v4 = q[4];
    a[0]=v0.x; a[1]=v0.y; a[2]=v0.z; a[3]=v0.w;
    a[4]=v1.x; a[5]=v1.y; a[6]=v1.z; a[7]=v1.w;
    a[8]=v2.x; a[9]=v2.y; a[10]=v2.z; a[11]=v2.w;
    a[12]=v3.x; a[13]=v3.y; a[14]=v3.z; a[15]=v3.w;
    a[16]=v4.x; a[17]=v4.y; a[18]=v4.z; a[19]=v4.w;
}

__device__ __forceinline__ float dot_bp(const float a[20], int base, float v) {
    float s = 0.f;
    #pragma unroll
    for (int m = 0; m < 20; ++m)
        s += a[m] * __uint_as_float(
            __builtin_amdgcn_ds_bpermute(base + (m << 2), (int)__float_as_uint(v)));
    return s;
}

// ---------------------------------------------------------------------------
// k_prepsmall (round-4 proven, verbatim)
// ---------------------------------------------------------------------------
__global__ __launch_bounds__(512) void k_prepsmall(const float* __restrict__ A,
                                                   const float* __restrict__ C,
                                                   float* __restrict__ ws) {
    __shared__ float aug[64][129];
    __shared__ float colk[64];
    __shared__ int   piv_s;
    __shared__ float rp_s;
    __shared__ float Xs[64][20];
    __shared__ float Ns[84][20];
    __shared__ float ANs[84][20];
    int tid = threadIdx.x;

    for (int id = tid; id < 64 * 64; id += 512) {
        int r = id >> 6, c = id & 63;
        aug[r][c]      = C[r * HID + c] + (r == c ? 1e-3f : 0.0f);
        aug[r][64 + c] = (r == c) ? 1.0f : 0.0f;
    }
    __syncthreads();

    for (int k = 0; k < 64; ++k) {
        if (tid < 64) {
            float v = (tid >= k) ? fabsf(aug[tid][k]) : -1.0f;
            int idx = tid;
            for (int off = 32; off; off >>= 1) {
                float v2 = __shfl_down(v, off);
                int   i2 = __shfl_down(idx, off);
                if (v2 > v) { v = v2; idx = i2; }
            }
            if (tid == 0) { piv_s = idx; rp_s = 1.0f / aug[idx][k]; }
        }
        __syncthreads();
        int p = piv_s;
        if (p != k) {
            for (int c = tid; c < 128; c += 512) {
                float tmp = aug[k][c]; aug[k][c] = aug[p][c]; aug[p][c] = tmp;
            }
        }
        __syncthreads();
        float rp = rp_s;
        for (int c = tid; c < 128; c += 512) aug[k][c] *= rp;
        __syncthreads();
        if (tid < 64) colk[tid] = aug[tid][k];
        __syncthreads();
        for (int id = tid; id < 64 * 128; id += 512) {
            int r = id >> 7, c = id & 127;
            if (r != k) aug[r][c] -= colk[r] * aug[k][c];
        }
        __syncthreads();
    }
    for (int id = tid; id < 64 * 64; id += 512) {
        int r = id >> 6, c = id & 63;
        ws[OFF_T1INV + r * 64 + c] = aug[r][64 + c];
    }
    __syncthreads();

    for (int id = tid; id < 64 * 20; id += 512) {
        int r = id / 20, j = id % 20;
        float s = 0.f;
        for (int c = 0; c < 64; ++c) s += aug[r][64 + c] * C[c * HID + 64 + j];
        Xs[r][j] = s;
        ws[OFF_XT + j * 64 + r] = s;
    }
    __syncthreads();
    for (int id = tid; id < HID * 20; id += 512) {
        int p = id / 20, j = id % 20;
        float v = (p < 64) ? -Xs[p][j] : ((p - 64) == j ? 1.f : 0.f);
        Ns[p][j] = v;
        ws[OFF_N + id] = v;
    }
    __syncthreads();
    for (int id = tid; id < HID * 20; id += 512) {
        int p = id / 20, j = id % 20;
        float s = 0.f;
        for (int m = 0; m < HID; ++m) s += A[p * HID + m] * Ns[m][j];
        ANs[p][j] = s;
        ws[OFF_AN + id] = s;
    }
    __syncthreads();
    for (int id = tid; id < 400; id += 512) {
        int a = id / 20, b = id % 20;
        float sn = 0.f, sf = 0.f, sg = 0.f;
        for (int p = 0; p < HID; ++p) {
            sn += Ns[p][a] * Ns[p][b];
            sf += Ns[p][a] * ANs[p][b];
            sg += ANs[p][a] * ANs[p][b];
        }
        ws[OFF_F + id]     = sf;
        ws[OFF_D + id]     = sn + sg;
        ws[OFF_DLAST + id] = sn;
    }
    for (int id = tid; id < 20 * 64; id += 512) {
        int j = id / 64, c = id % 64;
        float s1 = 0.f, s2 = 0.f;
        for (int p = 0; p < HID; ++p) {
            float av = A[p * HID + c];
            s1 += Ns[p][j] * av;
            s2 += ANs[p][j] * av;
        }
        ws[OFF_NA1 + id]  = s1;
        ws[OFF_ANA1 + id] = s2;
        ws[OFF_ANT1 + id] = ANs[c][j];
    }
}

// ---------------------------------------------------------------------------
// k_q (proven, verbatim)
// ---------------------------------------------------------------------------
__global__ __launch_bounds__(64) void k_q(const float* __restrict__ x,
                                          float* __restrict__ ws) {
    int i = blockIdx.x, b = blockIdx.y, r = threadIdx.x;
    __shared__ float yv[64];
    yv[r] = x[(b * TT + i) * 64 + r];
    __syncthreads();
    float s = 0.f;
    const float* Ti = ws + OFF_T1INV + r * 64;
    for (int c = 0; c < 64; ++c) s += Ti[c] * yv[c];
    ws[OFF_Q + (b * TT + i) * 64 + r] = s;
}

// ---------------------------------------------------------------------------
// k_g (proven, verbatim)
// ---------------------------------------------------------------------------
__global__ __launch_bounds__(64) void k_g(float* __restrict__ ws) {
    int i = blockIdx.x, b = blockIdx.y, tid = threadIdx.x;
    __shared__ float qi[64], qm[64], qp[64];
    const float* qb = ws + OFF_Q + b * TT * 64;
    qi[tid] = qb[i * 64 + tid];
    qm[tid] = (i > 0)  ? qb[(i - 1) * 64 + tid] : 0.f;
    qp[tid] = (i < 63) ? qb[(i + 1) * 64 + tid] : 0.f;
    __syncthreads();
    if (tid < 20) {
        const float* xt = ws + OFF_XT   + tid * 64;
        const float* na = ws + OFF_NA1  + tid * 64;
        const float* at = ws + OFF_ANT1 + tid * 64;
        const float* aa = ws + OFF_ANA1 + tid * 64;
        float s = 0.f;
        if (i < 63) {
            for (int c = 0; c < 64; ++c)
                s += xt[c] * qi[c] + na[c] * qm[c] + at[c] * qp[c] - aa[c] * qi[c];
        } else {
            for (int c = 0; c < 64; ++c)
                s += xt[c] * qi[c] + na[c] * qm[c];
        }
        ws[OFF_G + (i * 16 + b) * 20 + tid] = s;
    }
}

// ---------------------------------------------------------------------------
// k_sweep v2: spill-free factor. Constants D/Dlast/F live in LDS; wave 0
// keeps only w[40]+Kprev[20] in registers. Early exit at rel 1e-4 (safe:
// loss evaluated directly from t -> second-order insensitive). Skip iters
// copy converged FJ across the double-buffer parity. Backward sweep without
// deep prefetch (TLP across 8 waves hides J/Z L2 latency).
// ---------------------------------------------------------------------------
__global__ __launch_bounds__(576) void k_sweep(float* __restrict__ ws) {
    __shared__ float sD[400], sDl[400], sF[400];
    __shared__ float fjs[2][20][20];
    __shared__ int iconv_s;
    int tid = threadIdx.x, wave = tid >> 6, lane = tid & 63;

    for (int id = tid; id < 400; id += 576) {
        sD[id]  = ws[OFF_D + id];
        sDl[id] = ws[OFF_DLAST + id];
        sF[id]  = ws[OFF_F + id];
    }
    if (tid == 0) iconv_s = 63;

    float* G  = ws + OFF_G;
    float* Jg = ws + OFF_JG;
    float* Zg = ws + OFF_ZG;
    float* TS = ws + OFF_TS;

    float Kprev[20];
    #pragma unroll
    for (int r = 0; r < 20; ++r) Kprev[r] = 0.f;
    if (wave == 0) __builtin_amdgcn_s_setprio(1);

    int b = ((wave - 1) << 1) + (lane >> 5);
    int j = lane & 31;
    int jj = (j < 20) ? j : 0;
    bool actj = (wave >= 1) && (j < 20);
    int bpb = (lane & 32) << 2;
    float rt = 0.f, gnext = 0.f;
    if (actj) {
        rt    = G[(0 * 16 + b) * 20 + j];   // r~_0 = g_0
        gnext = G[(1 * 16 + b) * 20 + j];
    }
    __syncthreads();

    int iconv_loc = 63;
    for (int i = 0; i < TT; ++i) {
        if (wave == 0) {
            bool skip = (i > iconv_loc) && (i < 63);
            if (!skip) {
                float w[40];
                // build [ [E, F^T, I], [F, 0, 0] ] from LDS; lane owns a column
                #pragma unroll
                for (int r = 0; r < 20; ++r) {
                    float v, v2 = 0.f;
                    if (lane < 20) {
                        float dv = sD[r * 20 + lane];
                        if (i == 63) dv = sDl[r * 20 + lane];
                        v  = dv - Kprev[r];
                        v2 = sF[r * 20 + lane];
                    } else if (lane < 40) {
                        v = sF[(lane - 20) * 20 + r];        // F^T block
                    } else if (lane < 60) {
                        v = (r == lane - 40) ? 1.f : 0.f;    // I block
                    } else {
                        v = 0.f;
                    }
                    w[r]      = v;
                    w[20 + r] = v2;                           // [F 0 0]
                }
                // Gauss-Jordan, fully unrolled, approx-rcp pivots
                #pragma unroll
                for (int k = 0; k < 20; ++k) {
                    float rp = __builtin_amdgcn_rcpf(RDLANE(w[k], k));
                    w[k] *= rp;
                    #pragma unroll
                    for (int r = 0; r < 40; ++r) {
                        if (r == k) continue;
                        float ck = RDLANE(w[r], k);
                        w[r] -= ck * w[k];
                    }
                }
                // K_new gather (bottom-right block = -K) + convergence check
                float dmax = 0.f, kmax = 0.f;
                int gsel = (20 + lane) << 2;
                #pragma unroll
                for (int r = 0; r < 20; ++r) {
                    float kn = -__uint_as_float(__builtin_amdgcn_ds_bpermute(
                        gsel, (int)__float_as_uint(w[20 + r])));
                    dmax = fmaxf(dmax, fabsf(kn - Kprev[r]));
                    kmax = fmaxf(kmax, fabsf(kn));
                    Kprev[r] = kn;
                }
                if (i < 63 && iconv_loc == 63) {
                    if (__all((lane >= 20) || (dmax <= 1e-7f + 1e-4f * kmax))) {
                        iconv_loc = i;
                        if (lane == 0) iconv_s = i;
                    }
                }
                if (lane >= 40 && lane < 60) {
                    int c = lane - 40;
                    #pragma unroll
                    for (int r = 0; r < 20; ++r) {
                        Jg[i * 400 + r * 20 + c] = w[r];        // J row-major (sym)
                        Zg[i * 400 + c * 20 + r] = -w[20 + r];  // Z = (FJ)^T
                        fjs[i & 1][r][c]         = -w[20 + r];  // FJ publish
                    }
                }
            } else {
                // converged: propagate FJ_inf across the parity (read prev buf,
                // write cur buf; fwd waves read prev buf concurrently - RR ok)
                if (lane >= 40 && lane < 60) {
                    int c = lane - 40;
                    #pragma unroll
                    for (int r = 0; r < 20; ++r)
                        fjs[i & 1][r][c] = fjs[(i - 1) & 1][r][c];
                }
            }
        } else if (i >= 1) {
            // fwd step i: r~_i = g_i + FJ_{i-1} r~_{i-1}
            float fr[20];
            #pragma unroll
            for (int m = 0; m < 20; ++m) fr[m] = fjs[(i - 1) & 1][jj][m];
            rt = gnext + dot_bp(fr, bpb, rt);
            if (actj) {
                G[(i * 16 + b) * 20 + j] = rt;
                gnext = (i + 1 < TT) ? G[((i + 1) * 16 + b) * 20 + j] : 0.f;
            }
        }
        __syncthreads();
    }
    __threadfence_block();
    __syncthreads();

    // backward sweep: t_i = J_i r~_i + Z_i t_{i+1}, register-resident
    if (wave >= 1) {
        int icv = iconv_s;
        float tn;
        {
            float j63[20];
            ld20(Jg + 63 * 400 + jj * 20, j63);
            tn = dot_bp(j63, bpb, rt);                 // rt == r~_63
            if (actj) TS[(63 * 16 + b) * 20 + j] = tn;
        }
        for (int i = 62; i >= 0; --i) {
            int ix = (i < icv) ? i : icv;
            float jr[20], zr[20];
            ld20(Jg + ix * 400 + jj * 20, jr);
            ld20(Zg + ix * 400 + jj * 20, zr);
            float rtp = actj ? G[(i * 16 + b) * 20 + j] : 0.f;
            float t = dot_bp(jr, bpb, rtp) + dot_bp(zr, bpb, tn);
            if (actj) TS[(i * 16 + b) * 20 + j] = t;
            tn = t;
        }
    }
}

// ---------------------------------------------------------------------------
// k_loss (proven, verbatim)
// ---------------------------------------------------------------------------
__global__ __launch_bounds__(128) void k_loss(const float* __restrict__ A,
                                              float* __restrict__ ws) {
    int i = blockIdx.x + 1, b = blockIdx.y, tid = threadIdx.x;
    __shared__ float ti[20], tm[20], qi[64], qm[64];
    __shared__ float red[128];
    if (tid < 20) {
        ti[tid] = ws[OFF_TS + (i * 16 + b) * 20 + tid];
        tm[tid] = ws[OFF_TS + ((i - 1) * 16 + b) * 20 + tid];
    }
    if (tid < 64) {
        qi[tid] = ws[OFF_Q + (b * TT + i) * 64 + tid];
        qm[tid] = ws[OFF_Q + (b * TT + i - 1) * 64 + tid];
    }
    __syncthreads();
    float e = 0.f;
    if (tid < HID) {
        int p = tid;
        float s = (p < 64) ? qi[p] : 0.f;
        const float* Np  = ws + OFF_N  + p * 20;
        const float* ANp = ws + OFF_AN + p * 20;
        for (int j = 0; j < 20; ++j) s += Np[j] * ti[j] - ANp[j] * tm[j];
        const float* Ar = A + p * HID;
        for (int c = 0; c < 64; ++c) s -= Ar[c] * qm[c];
        e = s * s;
    }
    red[tid] = e;
    __syncthreads();
    for (int off = 64; off; off >>= 1) {
        if (tid < off) red[tid] += red[tid + off];
        __syncthreads();
    }
    if (tid == 0) ws[OFF_PART + b * 63 + (i - 1)] = red[0];
}

// ---------------------------------------------------------------------------
// k_reduce (proven, verbatim)
// ---------------------------------------------------------------------------
__global__ __launch_bounds__(256) void k_reduce(const float* __restrict__ ws,
                                                float* __restrict__ out) {
    __shared__ float red[256];
    int tid = threadIdx.x;
    float s = 0.f;
    for (int id = tid; id < BB * 63; id += 256) s += ws[OFF_PART + id];
    red[tid] = s;
    __syncthreads();
    for (int off = 128; off; off >>= 1) {
        if (tid < off) red[tid] += red[tid + off];
        __syncthreads();
    }
    if (tid == 0) out[0] = red[0] / (float)(BB * (TT - 1) * HID);
}

extern "C" void kernel_launch(void* const* d_in, const int* in_sizes, int n_in,
                              void* d_out, int out_size, void* d_ws, size_t ws_size,
                              hipStream_t stream) {
    (void)in_sizes; (void)n_in; (void)out_size; (void)ws_size;
    const float* x = (const float*)d_in[0];
    const float* A = (const float*)d_in[1];
    const float* C = (const float*)d_in[2];
    float* ws  = (float*)d_ws;
    float* out = (float*)d_out;

    k_prepsmall<<<dim3(1),          dim3(512), 0, stream>>>(A, C, ws);
    k_q        <<<dim3(TT, BB),     dim3(64),  0, stream>>>(x, ws);
    k_g        <<<dim3(TT, BB),     dim3(64),  0, stream>>>(ws);
    k_sweep    <<<dim3(1),          dim3(576), 0, stream>>>(ws);
    k_loss     <<<dim3(TT - 1, BB), dim3(128), 0, stream>>>(A, ws);
    k_reduce   <<<dim3(1),          dim3(256), 0, stream>>>(ws, out);
}

// Round 6
// 274.180 us; speedup vs baseline: 9.6644x; 1.1601x over previous
//
#include <hip/hip_runtime.h>

#define OBS 64
#define EXT 20
#define HID 84
#define TT  64
#define BB  16

// ws float offsets (total 172480 floats = ~690 KB)
#define OFF_T1INV 0        // 64x64
#define OFF_XT    4096     // 20x64
#define OFF_NA1   5376     // 20x64
#define OFF_ANT1  6656     // 20x64
#define OFF_ANA1  7936     // 20x64
#define OFF_N     9216     // 84x20
#define OFF_AN    10896    // 84x20
#define OFF_D     12576    // 20x20
#define OFF_DLAST 12976    // 20x20
#define OFF_F     13376    // 20x20
#define OFF_Q     13776    // [b][i][64]
#define OFF_G     79312    // [i][b][20] rhs g, overwritten in-place by r~
#define OFF_JG    99792    // [i][20][20] J_i row-major
#define OFF_ZG    125392   // [i][20][20] Z_i = J_i F^T row-major (= FJ^T)
#define OFF_TS    150992   // [i][b][20] solution t
#define OFF_PART  171472   // 1008 partial sums

#define RDLANE(v, l) __uint_as_float(__builtin_amdgcn_readlane((int)__float_as_uint(v), (l)))

__device__ __forceinline__ void ld20(const float* p, float a[20]) {
    const float4* q = (const float4*)p;
    float4 v0 = q[0], v1 = q[1], v2 = q[2], v3 = q[3], v4 = q[4];
    a[0]=v0.x; a[1]=v0.y; a[2]=v0.z; a[3]=v0.w;
    a[4]=v1.x; a[5]=v1.y; a[6]=v1.z; a[7]=v1.w;
    a[8]=v2.x; a[9]=v2.y; a[10]=v2.z; a[11]=v2.w;
    a[12]=v3.x; a[13]=v3.y; a[14]=v3.z; a[15]=v3.w;
    a[16]=v4.x; a[17]=v4.y; a[18]=v4.z; a[19]=v4.w;
}

__device__ __forceinline__ float dot_bp(const float a[20], int base, float v) {
    float s = 0.f;
    #pragma unroll
    for (int m = 0; m < 20; ++m)
        s += a[m] * __uint_as_float(
            __builtin_amdgcn_ds_bpermute(base + (m << 2), (int)__float_as_uint(v)));
    return s;
}

// ---------------------------------------------------------------------------
// k_prepsmall v2: virtual-pivot GJ (no row swaps), 2 barriers/step.
// Race-free: phase 1 (wave 0) snapshots the pivot row into prow[] and the
// scaled elimination column into fcol[]; phase 2 updates read ONLY prow/fcol.
// Permutation applied at extraction: T1inv[colof[r]][:] = aug[r][64:].
// Trailing constant-matrix section unchanged (proven), X reads T1inv from ws.
// ---------------------------------------------------------------------------
__global__ __launch_bounds__(512) void k_prepsmall(const float* __restrict__ A,
                                                   const float* __restrict__ C,
                                                   float* __restrict__ ws) {
    __shared__ float aug[64][129];
    __shared__ float prow[128];
    __shared__ float fcol[64];
    __shared__ int   colof[64];
    __shared__ float rp_s;
    __shared__ int   pv_s;
    __shared__ float Xs[64][20];
    __shared__ float Ns[84][20];
    __shared__ float ANs[84][20];
    int tid = threadIdx.x;

    for (int id = tid; id < 64 * 64; id += 512) {
        int r = id >> 6, c = id & 63;
        aug[r][c]      = C[r * HID + c] + (r == c ? 1e-3f : 0.0f);
        aug[r][64 + c] = (r == c) ? 1.0f : 0.0f;
    }
    __syncthreads();

    bool usedreg = false;   // meaningful for tid < 64 only
    for (int k = 0; k < 64; ++k) {
        if (tid < 64) {
            float a_rk = aug[tid][k];
            float v = usedreg ? -1.f : fabsf(a_rk);
            int idx = tid;
            for (int off = 32; off; off >>= 1) {
                float v2 = __shfl_down(v, off);
                int   i2 = __shfl_down(idx, off);
                if (v2 > v) { v = v2; idx = i2; }
            }
            int p = __shfl(idx, 0);
            float piv = __shfl(a_rk, p);
            float rp = 1.0f / piv;
            fcol[tid] = (tid == p) ? 0.f : a_rk * rp;
            prow[tid]      = aug[p][tid];
            prow[tid + 64] = aug[p][tid + 64];
            if (tid == p) { usedreg = true; colof[tid] = k; }
            if (tid == 0) { rp_s = rp; pv_s = p; }
        }
        __syncthreads();
        int p = pv_s;
        float rp = rp_s;
        int r = tid >> 3, c0 = (tid & 7) << 4;
        if (r == p) {
            #pragma unroll
            for (int cc = 0; cc < 16; ++cc) aug[p][c0 + cc] = prow[c0 + cc] * rp;
        } else {
            float fc = fcol[r];
            #pragma unroll
            for (int cc = 0; cc < 16; ++cc) aug[r][c0 + cc] -= fc * prow[c0 + cc];
        }
        __syncthreads();
    }
    // extract with permutation: row r of aug holds T1inv row colof[r]
    for (int id = tid; id < 64 * 64; id += 512) {
        int r = id >> 6, c = id & 63;
        ws[OFF_T1INV + colof[r] * 64 + c] = aug[r][64 + c];
    }
    __syncthreads();

    // X = T1inv @ T2 (T1inv read back from ws; same-workgroup visibility)
    for (int id = tid; id < 64 * 20; id += 512) {
        int r = id / 20, j = id % 20;
        float s = 0.f;
        const float* tr = ws + OFF_T1INV + r * 64;
        for (int c = 0; c < 64; ++c) s += tr[c] * C[c * HID + 64 + j];
        Xs[r][j] = s;
        ws[OFF_XT + j * 64 + r] = s;
    }
    __syncthreads();
    for (int id = tid; id < HID * 20; id += 512) {
        int p = id / 20, j = id % 20;
        float v = (p < 64) ? -Xs[p][j] : ((p - 64) == j ? 1.f : 0.f);
        Ns[p][j] = v;
        ws[OFF_N + id] = v;
    }
    __syncthreads();
    for (int id = tid; id < HID * 20; id += 512) {
        int p = id / 20, j = id % 20;
        float s = 0.f;
        for (int m = 0; m < HID; ++m) s += A[p * HID + m] * Ns[m][j];
        ANs[p][j] = s;
        ws[OFF_AN + id] = s;
    }
    __syncthreads();
    for (int id = tid; id < 400; id += 512) {
        int a = id / 20, b = id % 20;
        float sn = 0.f, sf = 0.f, sg = 0.f;
        for (int p = 0; p < HID; ++p) {
            sn += Ns[p][a] * Ns[p][b];
            sf += Ns[p][a] * ANs[p][b];
            sg += ANs[p][a] * ANs[p][b];
        }
        ws[OFF_F + id]     = sf;
        ws[OFF_D + id]     = sn + sg;
        ws[OFF_DLAST + id] = sn;
    }
    for (int id = tid; id < 20 * 64; id += 512) {
        int j = id / 64, c = id % 64;
        float s1 = 0.f, s2 = 0.f;
        for (int p = 0; p < HID; ++p) {
            float av = A[p * HID + c];
            s1 += Ns[p][j] * av;
            s2 += ANs[p][j] * av;
        }
        ws[OFF_NA1 + id]  = s1;
        ws[OFF_ANA1 + id] = s2;
        ws[OFF_ANT1 + id] = ANs[c][j];
    }
}

// ---------------------------------------------------------------------------
// k_q (proven, verbatim)
// ---------------------------------------------------------------------------
__global__ __launch_bounds__(64) void k_q(const float* __restrict__ x,
                                          float* __restrict__ ws) {
    int i = blockIdx.x, b = blockIdx.y, r = threadIdx.x;
    __shared__ float yv[64];
    yv[r] = x[(b * TT + i) * 64 + r];
    __syncthreads();
    float s = 0.f;
    const float* Ti = ws + OFF_T1INV + r * 64;
    for (int c = 0; c < 64; ++c) s += Ti[c] * yv[c];
    ws[OFF_Q + (b * TT + i) * 64 + r] = s;
}

// ---------------------------------------------------------------------------
// k_g (proven, verbatim)
// ---------------------------------------------------------------------------
__global__ __launch_bounds__(64) void k_g(float* __restrict__ ws) {
    int i = blockIdx.x, b = blockIdx.y, tid = threadIdx.x;
    __shared__ float qi[64], qm[64], qp[64];
    const float* qb = ws + OFF_Q + b * TT * 64;
    qi[tid] = qb[i * 64 + tid];
    qm[tid] = (i > 0)  ? qb[(i - 1) * 64 + tid] : 0.f;
    qp[tid] = (i < 63) ? qb[(i + 1) * 64 + tid] : 0.f;
    __syncthreads();
    if (tid < 20) {
        const float* xt = ws + OFF_XT   + tid * 64;
        const float* na = ws + OFF_NA1  + tid * 64;
        const float* at = ws + OFF_ANT1 + tid * 64;
        const float* aa = ws + OFF_ANA1 + tid * 64;
        float s = 0.f;
        if (i < 63) {
            for (int c = 0; c < 64; ++c)
                s += xt[c] * qi[c] + na[c] * qm[c] + at[c] * qp[c] - aa[c] * qi[c];
        } else {
            for (int c = 0; c < 64; ++c)
                s += xt[c] * qi[c] + na[c] * qm[c];
        }
        ws[OFF_G + (i * 16 + b) * 20 + tid] = s;
    }
}

// ---------------------------------------------------------------------------
// k_sweep v3: phase-separated, barrier-free steady state.
// Phase A: wave 0 alone iterates the Riccati factor ONLY until convergence
//   (exact if it never converges: all 63 interior + terminal computed),
//   storing J_i / Z_i to global; then the Dlast terminal solve -> J_63.
// One barrier. Phase B: 8 waves (2 batches each) run the fwd recursion with
//   NO barriers, reading FJ rows as Z columns (FJ = Z^T) from L1-hot global.
// One barrier (G visibility). Phase C: barrier-free bwd sweep (unchanged).
// ---------------------------------------------------------------------------
__global__ __launch_bounds__(512) void k_sweep(float* __restrict__ ws) {
    __shared__ float sD[400], sDl[400], sF[400];
    __shared__ int iconv_s;
    int tid = threadIdx.x, wave = tid >> 6, lane = tid & 63;

    for (int id = tid; id < 400; id += 512) {
        sD[id]  = ws[OFF_D + id];
        sDl[id] = ws[OFF_DLAST + id];
        sF[id]  = ws[OFF_F + id];
    }
    if (tid == 0) iconv_s = 62;
    __syncthreads();

    float* G  = ws + OFF_G;
    float* Jg = ws + OFF_JG;
    float* Zg = ws + OFF_ZG;
    float* TS = ws + OFF_TS;

    if (wave == 0) {
        float Kprev[20];
        #pragma unroll
        for (int r = 0; r < 20; ++r) Kprev[r] = 0.f;
        int iconv = 62;
        for (int i = 0; i < 64; ++i) {
            bool last = (i == 63);
            float w[40];
            #pragma unroll
            for (int r = 0; r < 20; ++r) {
                float v, v2 = 0.f;
                if (lane < 20) {
                    float dv = last ? sDl[r * 20 + lane] : sD[r * 20 + lane];
                    v  = dv - Kprev[r];
                    v2 = sF[r * 20 + lane];
                } else if (lane < 40) {
                    v = sF[(lane - 20) * 20 + r];          // F^T block
                } else if (lane < 60) {
                    v = (r == lane - 40) ? 1.f : 0.f;      // I block
                } else {
                    v = 0.f;
                }
                w[r]      = v;
                w[20 + r] = v2;                             // [F 0 0]
            }
            #pragma unroll
            for (int k = 0; k < 20; ++k) {
                float rp = __builtin_amdgcn_rcpf(RDLANE(w[k], k));
                w[k] *= rp;
                #pragma unroll
                for (int r = 0; r < 40; ++r) {
                    if (r == k) continue;
                    float ck = RDLANE(w[r], k);
                    w[r] -= ck * w[k];
                }
            }
            if (lane >= 40 && lane < 60) {
                int c = lane - 40;
                #pragma unroll
                for (int r = 0; r < 20; ++r) {
                    Jg[i * 400 + r * 20 + c] = w[r];          // J row-major (sym)
                    if (!last) Zg[i * 400 + c * 20 + r] = -w[20 + r]; // Z = (FJ)^T
                }
            }
            if (last) break;
            float dmax = 0.f, kmax = 0.f;
            int gsel = (20 + lane) << 2;
            #pragma unroll
            for (int r = 0; r < 20; ++r) {
                float kn = -__uint_as_float(__builtin_amdgcn_ds_bpermute(
                    gsel, (int)__float_as_uint(w[20 + r])));
                dmax = fmaxf(dmax, fabsf(kn - Kprev[r]));
                kmax = fmaxf(kmax, fabsf(kn));
                Kprev[r] = kn;
            }
            if (i < 62 && __all((lane >= 20) || (dmax <= 1e-7f + 1e-4f * kmax))) {
                iconv = i;
                i = 62;            // next loop iteration is the terminal (63)
            }
        }
        if (lane == 0) iconv_s = iconv;
    }
    __syncthreads();
    int icv = iconv_s;

    // ---- forward sweep, no barriers: r~_i = g_i + FJ_{min(i-1,icv)} r~_{i-1}
    int b = (wave << 1) + (lane >> 5);
    int j = lane & 31;
    int jj = (j < 20) ? j : 0;
    bool actj = (j < 20);
    int bpb = (lane & 32) << 2;
    float rt = 0.f, gnext = 0.f;
    if (actj) {
        rt    = G[(0 * 16 + b) * 20 + j];
        gnext = G[(1 * 16 + b) * 20 + j];
    }
    for (int i = 1; i < TT; ++i) {
        int ix = (i - 1 < icv) ? (i - 1) : icv;
        const float* zc = Zg + ix * 400 + jj;   // FJ row jj = Z column jj
        float fr[20];
        #pragma unroll
        for (int m = 0; m < 20; ++m) fr[m] = zc[m * 20];
        rt = gnext + dot_bp(fr, bpb, rt);
        if (actj) {
            G[(i * 16 + b) * 20 + j] = rt;
            gnext = (i + 1 < TT) ? G[((i + 1) * 16 + b) * 20 + j] : 0.f;
        }
    }
    __syncthreads();   // r~ visible (and vmcnt drained) for the bwd reads

    // ---- backward sweep, no barriers: t_i = J_i r~_i + Z_i t_{i+1}
    {
        float tn;
        float j63[20];
        ld20(Jg + 63 * 400 + jj * 20, j63);
        tn = dot_bp(j63, bpb, rt);              // rt == r~_63
        if (actj) TS[(63 * 16 + b) * 20 + j] = tn;
        for (int i = 62; i >= 0; --i) {
            int ix = (i < icv) ? i : icv;
            float jr[20], zr[20];
            ld20(Jg + ix * 400 + jj * 20, jr);
            ld20(Zg + ix * 400 + jj * 20, zr);
            float rtp = actj ? G[(i * 16 + b) * 20 + j] : 0.f;
            float t = dot_bp(jr, bpb, rtp) + dot_bp(zr, bpb, tn);
            if (actj) TS[(i * 16 + b) * 20 + j] = t;
            tn = t;
        }
    }
}

// ---------------------------------------------------------------------------
// k_loss (proven, verbatim)
// ---------------------------------------------------------------------------
__global__ __launch_bounds__(128) void k_loss(const float* __restrict__ A,
                                              float* __restrict__ ws) {
    int i = blockIdx.x + 1, b = blockIdx.y, tid = threadIdx.x;
    __shared__ float ti[20], tm[20], qi[64], qm[64];
    __shared__ float red[128];
    if (tid < 20) {
        ti[tid] = ws[OFF_TS + (i * 16 + b) * 20 + tid];
        tm[tid] = ws[OFF_TS + ((i - 1) * 16 + b) * 20 + tid];
    }
    if (tid < 64) {
        qi[tid] = ws[OFF_Q + (b * TT + i) * 64 + tid];
        qm[tid] = ws[OFF_Q + (b * TT + i - 1) * 64 + tid];
    }
    __syncthreads();
    float e = 0.f;
    if (tid < HID) {
        int p = tid;
        float s = (p < 64) ? qi[p] : 0.f;
        const float* Np  = ws + OFF_N  + p * 20;
        const float* ANp = ws + OFF_AN + p * 20;
        for (int j = 0; j < 20; ++j) s += Np[j] * ti[j] - ANp[j] * tm[j];
        const float* Ar = A + p * HID;
        for (int c = 0; c < 64; ++c) s -= Ar[c] * qm[c];
        e = s * s;
    }
    red[tid] = e;
    __syncthreads();
    for (int off = 64; off; off >>= 1) {
        if (tid < off) red[tid] += red[tid + off];
        __syncthreads();
    }
    if (tid == 0) ws[OFF_PART + b * 63 + (i - 1)] = red[0];
}

// ---------------------------------------------------------------------------
// k_reduce (proven, verbatim)
// ---------------------------------------------------------------------------
__global__ __launch_bounds__(256) void k_reduce(const float* __restrict__ ws,
                                                float* __restrict__ out) {
    __shared__ float red[256];
    int tid = threadIdx.x;
    float s = 0.f;
    for (int id = tid; id < BB * 63; id += 256) s += ws[OFF_PART + id];
    red[tid] = s;
    __syncthreads();
    for (int off = 128; off; off >>= 1) {
        if (tid < off) red[tid] += red[tid + off];
        __syncthreads();
    }
    if (tid == 0) out[0] = red[0] / (float)(BB * (TT - 1) * HID);
}

extern "C" void kernel_launch(void* const* d_in, const int* in_sizes, int n_in,
                              void* d_out, int out_size, void* d_ws, size_t ws_size,
                              hipStream_t stream) {
    (void)in_sizes; (void)n_in; (void)out_size; (void)ws_size;
    const float* x = (const float*)d_in[0];
    const float* A = (const float*)d_in[1];
    const float* C = (const float*)d_in[2];
    float* ws  = (float*)d_ws;
    float* out = (float*)d_out;

    k_prepsmall<<<dim3(1),          dim3(512), 0, stream>>>(A, C, ws);
    k_q        <<<dim3(TT, BB),     dim3(64),  0, stream>>>(x, ws);
    k_g        <<<dim3(TT, BB),     dim3(64),  0, stream>>>(ws);
    k_sweep    <<<dim3(1),          dim3(512), 0, stream>>>(ws);
    k_loss     <<<dim3(TT - 1, BB), dim3(128), 0, stream>>>(A, ws);
    k_reduce   <<<dim3(1),          dim3(256), 0, stream>>>(ws, out);
}

// Round 7
// 224.861 us; speedup vs baseline: 11.7841x; 1.2193x over previous
//
#include <hip/hip_runtime.h>

#define OBS 64
#define EXT 20
#define HID 84
#define TT  64
#define BB  16

// ws float offsets (total 172480 floats = ~690 KB)
#define OFF_T1INV 0        // 64x64
#define OFF_XT    4096     // 20x64
#define OFF_NA1   5376     // 20x64
#define OFF_ANT1  6656     // 20x64
#define OFF_ANA1  7936     // 20x64
#define OFF_N     9216     // 84x20
#define OFF_AN    10896    // 84x20
#define OFF_D     12576    // 20x20
#define OFF_DLAST 12976    // 20x20
#define OFF_F     13376    // 20x20
#define OFF_Q     13776    // [b][i][64]
#define OFF_G     79312    // [i][b][20] rhs g (read-only after k_qg)
#define OFF_JG    99792    // [i][20][20] J_i row-major
#define OFF_ZG    125392   // [i][20][20] Z_i = J_i F^T row-major (= FJ^T)
#define OFF_TS    150992   // [i][b][20] solution t
#define OFF_PART  171472   // 1008 partial sums
#define OFF_ICONV OFF_D    // k_factor writes iconv AFTER its last read of D

#define RDLANE(v, l) __uint_as_float(__builtin_amdgcn_readlane((int)__float_as_uint(v), (l)))

__device__ __forceinline__ void ld20(const float* p, float a[20]) {
    const float4* q = (const float4*)p;
    float4 v0 = q[0], v1 = q[1], v2 = q[2], v3 = q[3], v4 = q[4];
    a[0]=v0.x; a[1]=v0.y; a[2]=v0.z; a[3]=v0.w;
    a[4]=v1.x; a[5]=v1.y; a[6]=v1.z; a[7]=v1.w;
    a[8]=v2.x; a[9]=v2.y; a[10]=v2.z; a[11]=v2.w;
    a[12]=v3.x; a[13]=v3.y; a[14]=v3.z; a[15]=v3.w;
    a[16]=v4.x; a[17]=v4.y; a[18]=v4.z; a[19]=v4.w;
}

__device__ __forceinline__ float dot20(const float a[20], const float v[20]) {
    float s0 = 0.f, s1 = 0.f, s2 = 0.f, s3 = 0.f;
    #pragma unroll
    for (int m = 0; m < 20; m += 4) {
        s0 += a[m]     * v[m];
        s1 += a[m + 1] * v[m + 1];
        s2 += a[m + 2] * v[m + 2];
        s3 += a[m + 3] * v[m + 3];
    }
    return (s0 + s1) + (s2 + s3);
}

// ---------------------------------------------------------------------------
// k_prepsmall (round-6 proven, verbatim)
// ---------------------------------------------------------------------------
__global__ __launch_bounds__(512) void k_prepsmall(const float* __restrict__ A,
                                                   const float* __restrict__ C,
                                                   float* __restrict__ ws) {
    __shared__ float aug[64][129];
    __shared__ float prow[128];
    __shared__ float fcol[64];
    __shared__ int   colof[64];
    __shared__ float rp_s;
    __shared__ int   pv_s;
    __shared__ float Xs[64][20];
    __shared__ float Ns[84][20];
    __shared__ float ANs[84][20];
    int tid = threadIdx.x;

    for (int id = tid; id < 64 * 64; id += 512) {
        int r = id >> 6, c = id & 63;
        aug[r][c]      = C[r * HID + c] + (r == c ? 1e-3f : 0.0f);
        aug[r][64 + c] = (r == c) ? 1.0f : 0.0f;
    }
    __syncthreads();

    bool usedreg = false;
    for (int k = 0; k < 64; ++k) {
        if (tid < 64) {
            float a_rk = aug[tid][k];
            float v = usedreg ? -1.f : fabsf(a_rk);
            int idx = tid;
            for (int off = 32; off; off >>= 1) {
                float v2 = __shfl_down(v, off);
                int   i2 = __shfl_down(idx, off);
                if (v2 > v) { v = v2; idx = i2; }
            }
            int p = __shfl(idx, 0);
            float piv = __shfl(a_rk, p);
            float rp = 1.0f / piv;
            fcol[tid] = (tid == p) ? 0.f : a_rk * rp;
            prow[tid]      = aug[p][tid];
            prow[tid + 64] = aug[p][tid + 64];
            if (tid == p) { usedreg = true; colof[tid] = k; }
            if (tid == 0) { rp_s = rp; pv_s = p; }
        }
        __syncthreads();
        int p = pv_s;
        float rp = rp_s;
        int r = tid >> 3, c0 = (tid & 7) << 4;
        if (r == p) {
            #pragma unroll
            for (int cc = 0; cc < 16; ++cc) aug[p][c0 + cc] = prow[c0 + cc] * rp;
        } else {
            float fc = fcol[r];
            #pragma unroll
            for (int cc = 0; cc < 16; ++cc) aug[r][c0 + cc] -= fc * prow[c0 + cc];
        }
        __syncthreads();
    }
    for (int id = tid; id < 64 * 64; id += 512) {
        int r = id >> 6, c = id & 63;
        ws[OFF_T1INV + colof[r] * 64 + c] = aug[r][64 + c];
    }
    __syncthreads();

    for (int id = tid; id < 64 * 20; id += 512) {
        int r = id / 20, j = id % 20;
        float s = 0.f;
        const float* tr = ws + OFF_T1INV + r * 64;
        for (int c = 0; c < 64; ++c) s += tr[c] * C[c * HID + 64 + j];
        Xs[r][j] = s;
        ws[OFF_XT + j * 64 + r] = s;
    }
    __syncthreads();
    for (int id = tid; id < HID * 20; id += 512) {
        int p = id / 20, j = id % 20;
        float v = (p < 64) ? -Xs[p][j] : ((p - 64) == j ? 1.f : 0.f);
        Ns[p][j] = v;
        ws[OFF_N + id] = v;
    }
    __syncthreads();
    for (int id = tid; id < HID * 20; id += 512) {
        int p = id / 20, j = id % 20;
        float s = 0.f;
        for (int m = 0; m < HID; ++m) s += A[p * HID + m] * Ns[m][j];
        ANs[p][j] = s;
        ws[OFF_AN + id] = s;
    }
    __syncthreads();
    for (int id = tid; id < 400; id += 512) {
        int a = id / 20, b = id % 20;
        float sn = 0.f, sf = 0.f, sg = 0.f;
        for (int p = 0; p < HID; ++p) {
            sn += Ns[p][a] * Ns[p][b];
            sf += Ns[p][a] * ANs[p][b];
            sg += ANs[p][a] * ANs[p][b];
        }
        ws[OFF_F + id]     = sf;
        ws[OFF_D + id]     = sn + sg;
        ws[OFF_DLAST + id] = sn;
    }
    for (int id = tid; id < 20 * 64; id += 512) {
        int j = id / 64, c = id % 64;
        float s1 = 0.f, s2 = 0.f;
        for (int p = 0; p < HID; ++p) {
            float av = A[p * HID + c];
            s1 += Ns[p][j] * av;
            s2 += ANs[p][j] * av;
        }
        ws[OFF_NA1 + id]  = s1;
        ws[OFF_ANA1 + id] = s2;
        ws[OFF_ANT1 + id] = ANs[c][j];
    }
}

// ---------------------------------------------------------------------------
// k_factor: single wave; Riccati factor to convergence (round-6 Phase A,
// proven). iconv published to ws[OFF_ICONV] (after last read of D).
// ---------------------------------------------------------------------------
__global__ __launch_bounds__(64, 1) void k_factor(float* __restrict__ ws) {
    __shared__ float sD[400], sDl[400], sF[400];
    int lane = threadIdx.x;
    for (int id = lane; id < 400; id += 64) {
        sD[id]  = ws[OFF_D + id];
        sDl[id] = ws[OFF_DLAST + id];
        sF[id]  = ws[OFF_F + id];
    }
    __syncthreads();

    float* Jg = ws + OFF_JG;
    float* Zg = ws + OFF_ZG;

    float Kprev[20];
    #pragma unroll
    for (int r = 0; r < 20; ++r) Kprev[r] = 0.f;
    int iconv = 62;
    for (int i = 0; i < 64; ++i) {
        bool last = (i == 63);
        float w[40];
        #pragma unroll
        for (int r = 0; r < 20; ++r) {
            float v, v2 = 0.f;
            if (lane < 20) {
                float dv = last ? sDl[r * 20 + lane] : sD[r * 20 + lane];
                v  = dv - Kprev[r];
                v2 = sF[r * 20 + lane];
            } else if (lane < 40) {
                v = sF[(lane - 20) * 20 + r];          // F^T block
            } else if (lane < 60) {
                v = (r == lane - 40) ? 1.f : 0.f;      // I block
            } else {
                v = 0.f;
            }
            w[r]      = v;
            w[20 + r] = v2;                             // [F 0 0]
        }
        #pragma unroll
        for (int k = 0; k < 20; ++k) {
            float rp = __builtin_amdgcn_rcpf(RDLANE(w[k], k));
            w[k] *= rp;
            #pragma unroll
            for (int r = 0; r < 40; ++r) {
                if (r == k) continue;
                float ck = RDLANE(w[r], k);
                w[r] -= ck * w[k];
            }
        }
        if (lane >= 40 && lane < 60) {
            int c = lane - 40;
            #pragma unroll
            for (int r = 0; r < 20; ++r) {
                Jg[i * 400 + r * 20 + c] = w[r];                   // J row-major
                if (!last) Zg[i * 400 + c * 20 + r] = -w[20 + r];  // Z = (FJ)^T
            }
        }
        if (last) break;
        float dmax = 0.f, kmax = 0.f;
        int gsel = (20 + lane) << 2;
        #pragma unroll
        for (int r = 0; r < 20; ++r) {
            float kn = -__uint_as_float(__builtin_amdgcn_ds_bpermute(
                gsel, (int)__float_as_uint(w[20 + r])));
            dmax = fmaxf(dmax, fabsf(kn - Kprev[r]));
            kmax = fmaxf(kmax, fabsf(kn));
            Kprev[r] = kn;
        }
        if (i < 62 && __all((lane >= 20) || (dmax <= 1e-7f + 1e-4f * kmax))) {
            iconv = i;
            i = 62;            // next loop iteration is the terminal (63)
        }
    }
    if (lane == 0) ws[OFF_ICONV] = __int_as_float(iconv);
}

// ---------------------------------------------------------------------------
// k_qg: fused q+g. Block (i,b) recomputes q_{i-1},q_i,q_{i+1} (redundant but
// fully parallel), stores q_i, and computes g_i with the proven formula.
// ---------------------------------------------------------------------------
__global__ __launch_bounds__(64) void k_qg(const float* __restrict__ x,
                                           float* __restrict__ ws) {
    int i = blockIdx.x, b = blockIdx.y, r = threadIdx.x;
    __shared__ float yv[3][64];
    __shared__ float qs[3][64];
    yv[1][r] = x[(b * TT + i) * 64 + r];
    yv[0][r] = (i > 0)  ? x[(b * TT + i - 1) * 64 + r] : 0.f;
    yv[2][r] = (i < 63) ? x[(b * TT + i + 1) * 64 + r] : 0.f;
    __syncthreads();
    const float* Ti = ws + OFF_T1INV + r * 64;
    float q0 = 0.f, q1 = 0.f, q2 = 0.f;
    for (int c = 0; c < 64; ++c) {
        float t = Ti[c];
        q0 += t * yv[0][c];
        q1 += t * yv[1][c];
        q2 += t * yv[2][c];
    }
    qs[0][r] = q0; qs[1][r] = q1; qs[2][r] = q2;
    ws[OFF_Q + (b * TT + i) * 64 + r] = q1;
    __syncthreads();
    if (r < 20) {
        const float* xt = ws + OFF_XT   + r * 64;
        const float* na = ws + OFF_NA1  + r * 64;
        const float* at = ws + OFF_ANT1 + r * 64;
        const float* aa = ws + OFF_ANA1 + r * 64;
        float s = 0.f;
        if (i < 63) {
            for (int c = 0; c < 64; ++c)
                s += xt[c] * qs[1][c] + na[c] * qs[0][c] + at[c] * qs[2][c] - aa[c] * qs[1][c];
        } else {
            for (int c = 0; c < 64; ++c)
                s += xt[c] * qs[1][c] + na[c] * qs[0][c];
        }
        ws[OFF_G + (i * 16 + b) * 20 + r] = s;
    }
}

// ---------------------------------------------------------------------------
// k_sweeps: 8 independent 1-wave blocks, 2 batches each; fwd then bwd with
// ZERO barriers. Constant-region matrices (i >= icv) preloaded into
// REGISTERS; r~/t histories in per-block LDS, gathered via broadcast
// ds_read_b128 (5 reads) instead of 20 ds_bpermute.
// ---------------------------------------------------------------------------
__global__ __launch_bounds__(64, 1) void k_sweeps(float* __restrict__ ws) {
    __shared__ float rh[TT][2][20];   // r~ history per batch-half
    __shared__ float th[2][20];       // rolling t
    int lane = threadIdx.x;
    int bh   = lane >> 5;
    int b    = (blockIdx.x << 1) + bh;
    int j    = lane & 31;
    int jj   = (j < 20) ? j : 0;
    bool actj = (j < 20);

    int icv = __float_as_int(ws[OFF_ICONV]);
    const float* G  = ws + OFF_G;
    const float* Jg = ws + OFF_JG;
    const float* Zg = ws + OFF_ZG;
    float* TS = ws + OFF_TS;

    // constant-region rows in registers
    float Mrow[20];                       // FJ_infty row jj = Z_infty col jj
    #pragma unroll
    for (int m = 0; m < 20; ++m) Mrow[m] = Zg[icv * 400 + m * 20 + jj];
    float Jr[20], Zr[20], J63r[20];
    ld20(Jg + icv * 400 + jj * 20, Jr);
    ld20(Zg + icv * 400 + jj * 20, Zr);
    ld20(Jg + 63 * 400 + jj * 20, J63r);

    // ---- forward: r~_i = g_i + FJ_{min(i-1,icv)} r~_{i-1}
    float rt = 0.f, gnext = 0.f;
    if (actj) {
        rt    = G[(0 * 16 + b) * 20 + j];
        rh[0][bh][j] = rt;
        gnext = G[(1 * 16 + b) * 20 + j];
    }
    for (int i = 1; i < TT; ++i) {
        float rv[20];
        ld20(&rh[i - 1][bh][0], rv);      // 5x ds_read_b128 broadcast
        float s;
        if (i - 1 < icv) {
            float fr[20];
            #pragma unroll
            for (int m = 0; m < 20; ++m) fr[m] = Zg[(i - 1) * 400 + m * 20 + jj];
            s = gnext + dot20(fr, rv);
        } else {
            s = gnext + dot20(Mrow, rv);
        }
        rt = s;
        if (actj) {
            rh[i][bh][j] = rt;
            gnext = (i + 1 < TT) ? G[((i + 1) * 16 + b) * 20 + j] : 0.f;
        }
    }

    // ---- backward: t_i = J_i r~_i + Z_i t_{i+1}
    {
        float rv[20];
        ld20(&rh[63][bh][0], rv);
        float tn = dot20(J63r, rv);
        if (actj) {
            TS[(63 * 16 + b) * 20 + j] = tn;
            th[bh][j] = tn;
        }
        for (int i = 62; i >= 0; --i) {
            float rvi[20], tv[20];
            ld20(&rh[i][bh][0], rvi);
            ld20(&th[bh][0], tv);
            float t;
            if (i < icv) {
                float jr[20], zr[20];
                ld20(Jg + i * 400 + jj * 20, jr);
                ld20(Zg + i * 400 + jj * 20, zr);
                t = dot20(jr, rvi) + dot20(zr, tv);
            } else {
                t = dot20(Jr, rvi) + dot20(Zr, tv);
            }
            if (actj) {
                TS[(i * 16 + b) * 20 + j] = t;
                th[bh][j] = t;
            }
        }
    }
}

// ---------------------------------------------------------------------------
// k_loss (proven, verbatim)
// ---------------------------------------------------------------------------
__global__ __launch_bounds__(128) void k_loss(const float* __restrict__ A,
                                              float* __restrict__ ws) {
    int i = blockIdx.x + 1, b = blockIdx.y, tid = threadIdx.x;
    __shared__ float ti[20], tm[20], qi[64], qm[64];
    __shared__ float red[128];
    if (tid < 20) {
        ti[tid] = ws[OFF_TS + (i * 16 + b) * 20 + tid];
        tm[tid] = ws[OFF_TS + ((i - 1) * 16 + b) * 20 + tid];
    }
    if (tid < 64) {
        qi[tid] = ws[OFF_Q + (b * TT + i) * 64 + tid];
        qm[tid] = ws[OFF_Q + (b * TT + i - 1) * 64 + tid];
    }
    __syncthreads();
    float e = 0.f;
    if (tid < HID) {
        int p = tid;
        float s = (p < 64) ? qi[p] : 0.f;
        const float* Np  = ws + OFF_N  + p * 20;
        const float* ANp = ws + OFF_AN + p * 20;
        for (int j = 0; j < 20; ++j) s += Np[j] * ti[j] - ANp[j] * tm[j];
        const float* Ar = A + p * HID;
        for (int c = 0; c < 64; ++c) s -= Ar[c] * qm[c];
        e = s * s;
    }
    red[tid] = e;
    __syncthreads();
    for (int off = 64; off; off >>= 1) {
        if (tid < off) red[tid] += red[tid + off];
        __syncthreads();
    }
    if (tid == 0) ws[OFF_PART + b * 63 + (i - 1)] = red[0];
}

// ---------------------------------------------------------------------------
// k_reduce (proven, verbatim)
// ---------------------------------------------------------------------------
__global__ __launch_bounds__(256) void k_reduce(const float* __restrict__ ws,
                                                float* __restrict__ out) {
    __shared__ float red[256];
    int tid = threadIdx.x;
    float s = 0.f;
    for (int id = tid; id < BB * 63; id += 256) s += ws[OFF_PART + id];
    red[tid] = s;
    __syncthreads();
    for (int off = 128; off; off >>= 1) {
        if (tid < off) red[tid] += red[tid + off];
        __syncthreads();
    }
    if (tid == 0) out[0] = red[0] / (float)(BB * (TT - 1) * HID);
}

extern "C" void kernel_launch(void* const* d_in, const int* in_sizes, int n_in,
                              void* d_out, int out_size, void* d_ws, size_t ws_size,
                              hipStream_t stream) {
    (void)in_sizes; (void)n_in; (void)out_size; (void)ws_size;
    const float* x = (const float*)d_in[0];
    const float* A = (const float*)d_in[1];
    const float* C = (const float*)d_in[2];
    float* ws  = (float*)d_ws;
    float* out = (float*)d_out;

    k_prepsmall<<<dim3(1),          dim3(512), 0, stream>>>(A, C, ws);
    k_factor   <<<dim3(1),          dim3(64),  0, stream>>>(ws);
    k_qg       <<<dim3(TT, BB),     dim3(64),  0, stream>>>(x, ws);
    k_sweeps   <<<dim3(8),          dim3(64),  0, stream>>>(ws);
    k_loss     <<<dim3(TT - 1, BB), dim3(128), 0, stream>>>(A, ws);
    k_reduce   <<<dim3(1),          dim3(256), 0, stream>>>(ws, out);
}